// Round 4
// baseline (1280.101 us; speedup 1.0000x reference)
//
#include <hip/hip_runtime.h>
#include <hip/hip_bf16.h>

#define DEVI __device__ __forceinline__

typedef __attribute__((ext_vector_type(8))) __bf16 bf16x8;
typedef __attribute__((ext_vector_type(4))) float f32x4;
typedef __attribute__((ext_vector_type(4))) unsigned short u16x4;
typedef __attribute__((ext_vector_type(8))) unsigned short u16x8;

DEVI unsigned short f2bf(float f) {
  unsigned int u = __float_as_uint(f);
  u += 0x7FFFu + ((u >> 16) & 1u);   // RNE
  return (unsigned short)(u >> 16);
}

#define GLD16(g, l) __builtin_amdgcn_global_load_lds(                      \
    (const __attribute__((address_space(1))) void*)(g),                    \
    (__attribute__((address_space(3))) void*)(l), 16, 0, 0)

// ---------------------------------------------------------------- helpers

__global__ __launch_bounds__(256) void cast_k(const float* __restrict__ in,
                                              unsigned short* __restrict__ out,
                                              int n4) {
  for (int i = blockIdx.x * 256 + threadIdx.x; i < n4; i += gridDim.x * 256) {
    f32x4 v = ((const f32x4*)in)[i];
    u16x4 o;
    o.x = f2bf(v.x); o.y = f2bf(v.y); o.z = f2bf(v.z); o.w = f2bf(v.w);
    ((u16x4*)out)[i] = o;
  }
}

__global__ __launch_bounds__(256) void colnorm_k(const float* __restrict__ v,
                                                 const float* __restrict__ g,
                                                 float* __restrict__ s,
                                                 int rows, int cols) {
  const int tid = threadIdx.x;
  const int c0 = blockIdx.x * 64;
  const int c = tid & 63, rg = tid >> 6;
  float acc = 0.f;
  for (int i = rg; i < rows; i += 4) {
    float x = v[(size_t)i * cols + c0 + c];
    acc += x * x;
  }
  __shared__ float red[256];
  red[tid] = acc;
  __syncthreads();
  if (tid < 64) {
    float t = red[tid] + red[tid + 64] + red[tid + 128] + red[tid + 192];
    s[c0 + tid] = g[c0 + tid] * rsqrtf(t);
  }
}

__global__ __launch_bounds__(256) void scale_cast_k(const float* __restrict__ in,
                                                    const float* __restrict__ s,
                                                    unsigned short* __restrict__ out,
                                                    int cols, int n4) {
  const int cmask4 = (cols >> 2) - 1;
  for (int i = blockIdx.x * 256 + threadIdx.x; i < n4; i += gridDim.x * 256) {
    f32x4 v = ((const f32x4*)in)[i];
    f32x4 sv = ((const f32x4*)s)[i & cmask4];
    u16x4 o;
    o.x = f2bf(v.x * sv.x); o.y = f2bf(v.y * sv.y);
    o.z = f2bf(v.z * sv.z); o.w = f2bf(v.w * sv.w);
    ((u16x4*)out)[i] = o;
  }
}

// LayerNorm: one block per row of 2048 fp32, out bf16
__global__ __launch_bounds__(256) void ln_k(const float* __restrict__ x,
                                            const float* __restrict__ g,
                                            const float* __restrict__ b,
                                            unsigned short* __restrict__ out) {
  const int tid = threadIdx.x, lane = tid & 63, wid = tid >> 6;
  const int row = blockIdx.x;
  const float* xr = x + (size_t)row * 2048;
  f32x4 a0 = ((const f32x4*)xr)[tid];
  f32x4 a1 = ((const f32x4*)xr)[tid + 256];
  float s = a0.x + a0.y + a0.z + a0.w + a1.x + a1.y + a1.z + a1.w;
  float ss = a0.x * a0.x + a0.y * a0.y + a0.z * a0.z + a0.w * a0.w +
             a1.x * a1.x + a1.y * a1.y + a1.z * a1.z + a1.w * a1.w;
#pragma unroll
  for (int m = 1; m < 64; m <<= 1) {
    s += __shfl_xor(s, m);
    ss += __shfl_xor(ss, m);
  }
  __shared__ float red[8];
  if (lane == 0) { red[wid] = s; red[4 + wid] = ss; }
  __syncthreads();
  s = red[0] + red[1] + red[2] + red[3];
  ss = red[4] + red[5] + red[6] + red[7];
  const float mu = s * (1.f / 2048.f);
  const float var = ss * (1.f / 2048.f) - mu * mu;
  const float rs = rsqrtf(var + 1e-5f);
  f32x4 g0 = ((const f32x4*)g)[tid], g1 = ((const f32x4*)g)[tid + 256];
  f32x4 b0 = ((const f32x4*)b)[tid], b1 = ((const f32x4*)b)[tid + 256];
  u16x4 o0, o1;
  o0.x = f2bf((a0.x - mu) * rs * g0.x + b0.x);
  o0.y = f2bf((a0.y - mu) * rs * g0.y + b0.y);
  o0.z = f2bf((a0.z - mu) * rs * g0.z + b0.z);
  o0.w = f2bf((a0.w - mu) * rs * g0.w + b0.w);
  o1.x = f2bf((a1.x - mu) * rs * g1.x + b1.x);
  o1.y = f2bf((a1.y - mu) * rs * g1.y + b1.y);
  o1.z = f2bf((a1.z - mu) * rs * g1.z + b1.z);
  o1.w = f2bf((a1.w - mu) * rs * g1.w + b1.w);
  unsigned short* orow = out + (size_t)row * 2048;
  *(u16x4*)(orow + 4 * tid) = o0;
  *(u16x4*)(orow + 1024 + 4 * tid) = o1;
}

// V transpose: v [32][2048][128] -> vt [32][128][2048]
__global__ __launch_bounds__(256) void vtrans_k(const unsigned short* __restrict__ v,
                                                unsigned short* __restrict__ vt) {
  __shared__ unsigned short t[64][134];
  const int tid = threadIdx.x;
  const int bh = blockIdx.x >> 5, st = blockIdx.x & 31;
  const unsigned short* vb = v + ((size_t)bh << 18) + ((size_t)(st << 6) << 7);
#pragma unroll
  for (int i = 0; i < 4; ++i) {
    int f = tid + (i << 8);
    int row = f >> 4, c8 = f & 15;
    u16x8 x = *(const u16x8*)(vb + row * 128 + c8 * 8);
#pragma unroll
    for (int j = 0; j < 4; ++j) {
      unsigned int pk = ((unsigned int)x[2 * j + 1] << 16) | x[2 * j];
      *(unsigned int*)&t[row][c8 * 8 + 2 * j] = pk;
    }
  }
  __syncthreads();
  const int lane = tid & 63, wid = tid >> 6;
  unsigned short* ob = vt + ((size_t)bh << 18) + (st << 6);
#pragma unroll
  for (int j = 0; j < 32; ++j) {
    int d = (wid << 5) + j;
    ob[((size_t)d << 11) + lane] = t[lane][d];
  }
}

// ---------------------------------------------------------------- GEMM params
struct GemmP {
  const unsigned short* A;
  const unsigned short* B;
  const float* bias;
  const float* res;
  float* outF;
  unsigned short* outH;
  unsigned short* q;
  unsigned short* k;
  unsigned short* vt;   // EPI0: v (row-major [B,H,S,D])
  int M, N, K;
};

// ---------------------------------------------------------------- 128^2 GEMM (2-phase)
// +bias +res -> fp32. (m0,n0) from the wrapper's XCD-chunked mapping.
DEVI void gemm128_body(const GemmP& p, int m0, int n0) {
  const int tid = threadIdx.x, lane = tid & 63, wid = tid >> 6;
  const int K = p.K;
  const int wr = wid >> 1, wc = wid & 1;

  __shared__ __align__(16) unsigned short sA[2][4096];
  __shared__ __align__(16) unsigned short sB[2][4096];

  const int c0 = tid, c1 = tid + 256;
  const unsigned short* gA0 = p.A + (size_t)(m0 + (c0 >> 2)) * K + ((c0 & 3) << 3);
  const unsigned short* gA1 = p.A + (size_t)(m0 + (c1 >> 2)) * K + ((c1 & 3) << 3);
  const unsigned short* gB0 = p.B + (size_t)(n0 + (c0 >> 2)) * K + ((c0 & 3) << 3);
  const unsigned short* gB1 = p.B + (size_t)(n0 + (c1 >> 2)) * K + ((c1 & 3) << 3);
  const int l0 = wid << 9, l1 = (wid << 9) + 2048;

  f32x4 acc[4][4] = {};
  const int arow = (wr << 6) + (lane & 15);
  const int brow = (wc << 6) + (lane & 15);
  const int koff = (lane >> 4) << 3;

#define STAGE128(bufi, t) do { int ko = (t) << 5;       \
    GLD16(gA0 + ko, &sA[bufi][l0]);                     \
    GLD16(gA1 + ko, &sA[bufi][l1]);                     \
    GLD16(gB0 + ko, &sB[bufi][l0]);                     \
    GLD16(gB1 + ko, &sB[bufi][l1]); } while (0)

  STAGE128(0, 0);
  __syncthreads();
  const int nk = K >> 5;
  int cur = 0;
  for (int t = 0; t < nk; ++t) {
    if (t + 1 < nk) STAGE128(cur ^ 1, t + 1);
    bf16x8 af[4], bfr[4];
#pragma unroll
    for (int i = 0; i < 4; ++i)
      af[i] = *(const bf16x8*)&sA[cur][(arow + (i << 4)) * 32 + koff];
#pragma unroll
    for (int i = 0; i < 4; ++i)
      bfr[i] = *(const bf16x8*)&sB[cur][(brow + (i << 4)) * 32 + koff];
#pragma unroll
    for (int i = 0; i < 4; ++i)
#pragma unroll
      for (int j = 0; j < 4; ++j)
        acc[i][j] = __builtin_amdgcn_mfma_f32_16x16x32_bf16(af[i], bfr[j], acc[i][j], 0, 0, 0);
    __syncthreads();
    cur ^= 1;
  }
#undef STAGE128

  const int rbase = m0 + (wr << 6) + ((lane >> 4) << 2);
  const int cbase = n0 + (wc << 6) + (lane & 15);
#pragma unroll
  for (int mi = 0; mi < 4; ++mi) {
#pragma unroll
    for (int ni = 0; ni < 4; ++ni) {
      const int col = cbase + (ni << 4);
      const float bb = p.bias[col];
#pragma unroll
      for (int r = 0; r < 4; ++r) {
        const int row = rbase + (mi << 4) + r;
        float v = acc[mi][ni][r] + bb;
        const size_t o = (size_t)row * p.N + col;
        p.outF[o] = v + p.res[o];
      }
    }
  }
}

// M=4096,N=2048 (nbm=32,nbn=16): 8x8 tile region per XCD, n-fastest in-region
__global__ __launch_bounds__(256) void g2_proj128(GemmP p) {
  const int x = blockIdx.x & 7, i = blockIdx.x >> 3;  // i in [0,64)
  const int bm = (x >> 1) * 8 + (i >> 3);
  const int bn = (x & 1) * 8 + (i & 7);
  gemm128_body(p, bm << 7, bn << 7);
}
__global__ __launch_bounds__(256) void g4_out128(GemmP p) {
  const int x = blockIdx.x & 7, i = blockIdx.x >> 3;
  const int bm = (x >> 1) * 8 + (i >> 3);
  const int bn = (x & 1) * 8 + (i & 7);
  gemm128_body(p, bm << 7, bn << 7);
}

// ---------------------------------------------------------------- 256^2 tile common
DEVI void setup256(const GemmP& p, int m0, int n0,
                   const unsigned short*& gsA0, const unsigned short*& gsA1,
                   const unsigned short*& gsB0, const unsigned short*& gsB1) {
  const int tid = threadIdx.x;
  int r_[2], c_[2];
#pragma unroll
  for (int j = 0; j < 2; ++j) {
    int d = tid * 16 + j * 8192;
    int w = (d & 1023) ^ (((d >> 9) & 1) << 5);   // st_16x32 involution
    r_[j] = ((d >> 10) << 4) + (w >> 6);
    c_[j] = (w & 63) >> 1;
  }
  gsA0 = p.A + (size_t)(m0 + r_[0]) * p.K + c_[0];
  gsA1 = p.A + (size_t)(m0 + r_[1]) * p.K + c_[1];
  gsB0 = p.B + (size_t)(n0 + r_[0]) * p.K + c_[0];
  gsB1 = p.B + (size_t)(n0 + r_[1]) * p.K + c_[1];
}

// epilogue: EPI 0 = +bias, scatter q/k/v   EPI 2 = +bias, fast-GELU -> bf16
template <int EPI>
DEVI void epi256(const GemmP& p, f32x4 (&acc)[8][4], int m0, int n0) {
  const int lane = threadIdx.x & 63, wid = threadIdx.x >> 6;
  const int wr = wid >> 2, wc = wid & 3;
  const int lr = lane & 15, lk = lane >> 4;
  const int rbase = m0 + wr * 128 + (lk << 2);
  const int cbase = n0 + wc * 64 + lr;
#pragma unroll
  for (int m = 0; m < 8; ++m) {
#pragma unroll
    for (int n = 0; n < 4; ++n) {
      const int col = cbase + (n << 4);
      const float bb = p.bias[col];
#pragma unroll
      for (int r = 0; r < 4; ++r) {
        const int row = rbase + (m << 4) + r;
        float v = acc[m][n][r] + bb;
        if constexpr (EPI == 0) {
          const int gsel = col >> 11, e = col & 2047;
          const int h = e >> 7, d = e & 127;
          const int b2 = row >> 11, sidx = row & 2047;
          const size_t off = ((size_t)(b2 * 16 + h) << 18) + ((size_t)sidx << 7) + d;
          unsigned short hv = f2bf(v);
          if (gsel == 0)      p.q[off] = hv;
          else if (gsel == 1) p.k[off] = hv;
          else                p.vt[off] = hv;   // v row-major; transposed later
        } else {
          float y = 0.7978845608028654f * (v + 0.044715f * v * v * v);
          float u = __expf(2.f * y);
          float gl = (y > 40.f) ? v : v * (u / (u + 1.f));
          p.outH[(size_t)row * p.N + col] = f2bf(gl);
        }
      }
    }
  }
}

// ---------------------------------------------------------------- 256^2 GEMM, 8-phase
// (8 waves, BK=32, ring-4, prefetch depth 3, counted vmcnt, st_16x32 swizzle)
template <int EPI>
DEVI void gemm8p_body(const GemmP& p, unsigned short* lds_raw, int m0, int n0) {
  const int tid = threadIdx.x, lane = tid & 63, wid = tid >> 6;
  const int wr = wid >> 2, wc = wid & 3;
  const int lr = lane & 15, lk = lane >> 4;
  const int fb = (lr * 64 + lk * 16) ^ ((lr & 8) << 2);

  const unsigned short *gsA0, *gsA1, *gsB0, *gsB1;
  setup256(p, m0, n0, gsA0, gsA1, gsB0, gsB1);

#define STAGE_A8(b, kt) do { unsigned short* _d = lds_raw + ((b) << 14);       \
    GLD16(gsA0 + ((size_t)(kt) << 5), _d + (tid << 3));                        \
    GLD16(gsA1 + ((size_t)(kt) << 5), _d + 4096 + (tid << 3)); } while (0)
#define STAGE_B8(b, kt) do { unsigned short* _d = lds_raw + ((b) << 14) + 8192;\
    GLD16(gsB0 + ((size_t)(kt) << 5), _d + (tid << 3));                        \
    GLD16(gsB1 + ((size_t)(kt) << 5), _d + 4096 + (tid << 3)); } while (0)

  f32x4 acc[8][4] = {};
  const int NK = p.K >> 5;

  STAGE_A8(0, 0); STAGE_B8(0, 0);
  STAGE_A8(1, 1); STAGE_B8(1, 1);
  STAGE_A8(2, 2); STAGE_B8(2, 2);
  asm volatile("s_waitcnt vmcnt(8)" ::: "memory");
  __builtin_amdgcn_s_barrier();

  for (int t = 0; t < NK; ++t) {
    const int bi = t & 3;
    const char* tA = (const char*)(lds_raw + (bi << 14));
    const char* tB = (const char*)(lds_raw + (bi << 14) + 8192);
    bf16x8 a_[4], b_[4];
#pragma unroll
    for (int n = 0; n < 4; ++n)
      b_[n] = *(const bf16x8*)(tB + (((wc << 2) + n) << 10) + fb);
#pragma unroll
    for (int m = 0; m < 4; ++m)
      a_[m] = *(const bf16x8*)(tA + (((wr << 3) + m) << 10) + fb);
    if (t + 3 < NK) STAGE_A8((t + 3) & 3, t + 3);
    __builtin_amdgcn_s_barrier();
    asm volatile("s_waitcnt lgkmcnt(0)" ::: "memory");
    __builtin_amdgcn_sched_barrier(0);
    __builtin_amdgcn_s_setprio(1);
#pragma unroll
    for (int m = 0; m < 4; ++m)
#pragma unroll
      for (int n = 0; n < 4; ++n)
        acc[m][n] = __builtin_amdgcn_mfma_f32_16x16x32_bf16(a_[m], b_[n], acc[m][n], 0, 0, 0);
    __builtin_amdgcn_s_setprio(0);
    __builtin_amdgcn_s_barrier();
#pragma unroll
    for (int m = 0; m < 4; ++m)
      a_[m] = *(const bf16x8*)(tA + (((wr << 3) + 4 + m) << 10) + fb);
    if (t + 3 < NK) STAGE_B8((t + 3) & 3, t + 3);
    if (t + 3 < NK)      asm volatile("s_waitcnt vmcnt(8)" ::: "memory");
    else if (t + 2 < NK) asm volatile("s_waitcnt vmcnt(4)" ::: "memory");
    else if (t + 1 < NK) asm volatile("s_waitcnt vmcnt(0)" ::: "memory");
    __builtin_amdgcn_s_barrier();
    asm volatile("s_waitcnt lgkmcnt(0)" ::: "memory");
    __builtin_amdgcn_sched_barrier(0);
    __builtin_amdgcn_s_setprio(1);
#pragma unroll
    for (int m = 0; m < 4; ++m)
#pragma unroll
      for (int n = 0; n < 4; ++n)
        acc[4 + m][n] = __builtin_amdgcn_mfma_f32_16x16x32_bf16(a_[m], b_[n], acc[4 + m][n], 0, 0, 0);
    __builtin_amdgcn_s_setprio(0);
    __builtin_amdgcn_s_barrier();
  }
#undef STAGE_A8
#undef STAGE_B8
  epi256<EPI>(p, acc, m0, n0);
}

// ---------------------------------------------------------------- 256^2 GEMM, 2-phase
// A/B arm: identical staging/swizzle/fragments, plain dbuf + __syncthreads schedule.
template <int EPI>
DEVI void gemm2p_body(const GemmP& p, unsigned short* lds_raw, int m0, int n0) {
  const int tid = threadIdx.x, lane = tid & 63, wid = tid >> 6;
  const int wr = wid >> 2, wc = wid & 3;
  const int lr = lane & 15, lk = lane >> 4;
  const int fb = (lr * 64 + lk * 16) ^ ((lr & 8) << 2);

  const unsigned short *gsA0, *gsA1, *gsB0, *gsB1;
  setup256(p, m0, n0, gsA0, gsA1, gsB0, gsB1);

#define STG2(b, kt) do { unsigned short* _d = lds_raw + ((b) << 14);     \
    GLD16(gsA0 + ((size_t)(kt) << 5), _d + (tid << 3));                  \
    GLD16(gsA1 + ((size_t)(kt) << 5), _d + 4096 + (tid << 3));           \
    GLD16(gsB0 + ((size_t)(kt) << 5), _d + 8192 + (tid << 3));           \
    GLD16(gsB1 + ((size_t)(kt) << 5), _d + 12288 + (tid << 3)); } while (0)

  f32x4 acc[8][4] = {};
  const int NK = p.K >> 5;
  STG2(0, 0);
  __syncthreads();
  int cur = 0;
  for (int t = 0; t < NK; ++t) {
    if (t + 1 < NK) STG2(cur ^ 1, t + 1);
    const char* tA = (const char*)(lds_raw + (cur << 14));
    const char* tB = tA + 16384;
    bf16x8 a_[8], b_[4];
#pragma unroll
    for (int n = 0; n < 4; ++n)
      b_[n] = *(const bf16x8*)(tB + (((wc << 2) + n) << 10) + fb);
#pragma unroll
    for (int m = 0; m < 8; ++m)
      a_[m] = *(const bf16x8*)(tA + (((wr << 3) + m) << 10) + fb);
#pragma unroll
    for (int m = 0; m < 8; ++m)
#pragma unroll
      for (int n = 0; n < 4; ++n)
        acc[m][n] = __builtin_amdgcn_mfma_f32_16x16x32_bf16(a_[m], b_[n], acc[m][n], 0, 0, 0);
    __syncthreads();
    cur ^= 1;
  }
#undef STG2
  epi256<EPI>(p, acc, m0, n0);
}

// G1: qkv (M=4096,N=6144) nbm=16,nbn=24; region 8x6 per XCD
__global__ __launch_bounds__(512, 2) void g1_qkv8p(GemmP p) {
  extern __shared__ unsigned short lds_raw[];
  const int x = blockIdx.x & 7, i = blockIdx.x >> 3;  // i in [0,48)
  const int bm = (x >> 2) * 8 + i / 6;
  const int bn = (x & 3) * 6 + i % 6;
  gemm8p_body<0>(p, lds_raw, bm << 8, bn << 8);
}
// G3a: rows [0,2048) of fc, 8-phase. nbm=8,nbn=32; region 4x8 per XCD
__global__ __launch_bounds__(512, 2) void g3a_fc8p(GemmP p) {
  extern __shared__ unsigned short lds_raw[];
  const int x = blockIdx.x & 7, i = blockIdx.x >> 3;  // i in [0,32)
  const int bm = (x >> 2) * 4 + (i >> 3);
  const int bn = (x & 3) * 8 + (i & 7);
  gemm8p_body<2>(p, lds_raw, bm << 8, bn << 8);
}
// G3b: rows [2048,4096) of fc, 2-phase (the A/B control)
__global__ __launch_bounds__(512, 2) void g3b_fc2p(GemmP p) {
  extern __shared__ unsigned short lds_raw[];
  const int x = blockIdx.x & 7, i = blockIdx.x >> 3;  // i in [0,32)
  const int bm = (x >> 2) * 4 + (i >> 3);
  const int bn = (x & 3) * 8 + (i & 7);
  gemm2p_body<2>(p, lds_raw, 2048 + (bm << 8), bn << 8);
}

// ---------------------------------------------------------------- attention
// Q,K in [B,H,S,D]; V^T in [B,H,D,S]; O bf16 [4096,2048].
// Reg-staged K/V prefetch (T14) + defer-max rescale (T13, THR=8).
__global__ __launch_bounds__(256) void attn_k(const unsigned short* __restrict__ Q,
                                              const unsigned short* __restrict__ Kg,
                                              const unsigned short* __restrict__ Vt,
                                              unsigned short* __restrict__ O) {
  const int tid = threadIdx.x, lane = tid & 63, wid = tid >> 6;
  const int bid = blockIdx.x;
  const int pos = bid >> 3;
  const int bh = (bid & 7) * 4 + (pos >> 5);
  const int qt = pos & 31;
  const int q0 = qt * 64 + wid * 16;
  const int b = bh >> 4, h = bh & 15;

  __shared__ __align__(16) unsigned short sK[64 * 128];
  __shared__ __align__(16) unsigned short sV[128 * 64];
  __shared__ __align__(16) unsigned short sP[4][16 * 72];

  const unsigned short* Qb = Q + ((size_t)bh << 18);
  const unsigned short* Kb = Kg + ((size_t)bh << 18);
  const unsigned short* Vb = Vt + ((size_t)bh << 18);

  bf16x8 qf[4];
  {
    const unsigned short* qp = Qb + (size_t)(q0 + (lane & 15)) * 128 + ((lane >> 4) << 3);
#pragma unroll
    for (int kk = 0; kk < 4; ++kk) qf[kk] = *(const bf16x8*)(qp + kk * 32);
  }

  // per-thread pre-swizzled source offsets (same layout as old GLD16 path)
  int koffs[4], voffs[4];
#pragma unroll
  for (int i = 0; i < 4; ++i) {
    const int c = tid + (i << 8);
    const int kv = c >> 4, jj = c & 15;
    const int js = (jj & 8) | ((jj ^ kv) & 7);
    koffs[i] = kv * 128 + (js << 3);
    const int d = c >> 3, j2 = c & 7;
    const int js2 = j2 ^ (d & 7);
    voffs[i] = d * 2048 + (js2 << 3);
  }
  u16x8 kreg[4], vreg[4];
  auto PREF = [&](int kt) {
    const int kv0 = kt << 6;
#pragma unroll
    for (int i = 0; i < 4; ++i) {
      kreg[i] = *(const u16x8*)(Kb + kv0 * 128 + koffs[i]);
      vreg[i] = *(const u16x8*)(Vb + kv0 + voffs[i]);
    }
  };

  f32x4 oacc[8] = {};
  float mrun = -3e38f, lrun = 0.f;
  PREF(0);

  for (int kt = 0; kt < 32; ++kt) {
    // commit prefetched tile to LDS
#pragma unroll
    for (int i = 0; i < 4; ++i) {
      const int c8 = (tid + (i << 8)) << 3;
      *(u16x8*)&sK[c8] = kreg[i];
      *(u16x8*)&sV[c8] = vreg[i];
    }
    __syncthreads();
    if (kt + 1 < 32) PREF(kt + 1);   // HBM latency hides under compute below

    // S^T = K @ Q^T : lane holds q=lane&15, 16 kv values
    f32x4 sc[4] = {};
#pragma unroll
    for (int ti = 0; ti < 4; ++ti) {
#pragma unroll
      for (int kk = 0; kk < 4; ++kk) {
        const int row = (ti << 4) + (lane & 15);
        int bo = (row << 8) + (kk << 6) + ((lane >> 4) << 4);
        bo ^= (row & 7) << 4;
        bf16x8 kf = *(const bf16x8*)((const char*)sK + bo);
        sc[ti] = __builtin_amdgcn_mfma_f32_16x16x32_bf16(kf, qf[kk], sc[ti], 0, 0, 0);
      }
    }

    float pv[16];
    float mx = -3e38f;
#pragma unroll
    for (int ti = 0; ti < 4; ++ti)
#pragma unroll
      for (int r = 0; r < 4; ++r) {
        float x = sc[ti][r] * 0.08838834764831845f;
        pv[(ti << 2) + r] = x;
        mx = fmaxf(mx, x);
      }
    mx = fmaxf(mx, __shfl_xor(mx, 16));
    mx = fmaxf(mx, __shfl_xor(mx, 32));

    float corr = 1.f;
    if (!__all(mx - mrun <= 8.f)) {   // defer-max: rescale only on real growth
      const float mnew = fmaxf(mrun, mx);
      corr = __expf(mrun - mnew);
      mrun = mnew;
      float fr[4];
#pragma unroll
      for (int r = 0; r < 4; ++r) fr[r] = __shfl(corr, ((lane >> 4) << 2) + r);
#pragma unroll
      for (int di = 0; di < 8; ++di)
#pragma unroll
        for (int r = 0; r < 4; ++r) oacc[di][r] *= fr[r];
    }
    float psum = 0.f;
#pragma unroll
    for (int i2 = 0; i2 < 16; ++i2) {
      float e = __expf(pv[i2] - mrun);   // bounded by e^8 in deferred state
      pv[i2] = e;
      psum += e;
    }
    psum += __shfl_xor(psum, 16);
    psum += __shfl_xor(psum, 32);
    lrun = lrun * corr + psum;

    unsigned short* prow = &sP[wid][(lane & 15) * 72];
#pragma unroll
    for (int ti = 0; ti < 4; ++ti) {
      u16x4 w4;
      w4.x = f2bf(pv[(ti << 2) + 0]);
      w4.y = f2bf(pv[(ti << 2) + 1]);
      w4.z = f2bf(pv[(ti << 2) + 2]);
      w4.w = f2bf(pv[(ti << 2) + 3]);
      *(u16x4*)&prow[(ti << 4) + ((lane >> 4) << 2)] = w4;
    }

    // O += P @ V
#pragma unroll
    for (int di = 0; di < 8; ++di) {
#pragma unroll
      for (int ks = 0; ks < 2; ++ks) {
        bf16x8 pf = *(const bf16x8*)((const char*)&sP[wid][0] +
                                     (lane & 15) * 144 + (ks << 6) + ((lane >> 4) << 4));
        const int dr = (di << 4) + (lane & 15);
        int bo = (dr << 7) + (ks << 6) + ((lane >> 4) << 4);
        bo ^= (dr & 7) << 4;
        bf16x8 vf = *(const bf16x8*)((const char*)sV + bo);
        oacc[di] = __builtin_amdgcn_mfma_f32_16x16x32_bf16(pf, vf, oacc[di], 0, 0, 0);
      }
    }
    __syncthreads();
  }

  float il[4];
#pragma unroll
  for (int r = 0; r < 4; ++r) il[r] = 1.f / __shfl(lrun, ((lane >> 4) << 2) + r);
  const size_t obase = ((size_t)(b * 2048 + q0)) * 2048 + h * 128;
#pragma unroll
  for (int di = 0; di < 8; ++di)
#pragma unroll
    for (int r = 0; r < 4; ++r) {
      const size_t o = obase + (size_t)(((lane >> 4) << 2) + r) * 2048 + (di << 4) + (lane & 15);
      O[o] = f2bf(oacc[di][r] * il[r]);
    }
}

// ---------------------------------------------------------------- launch

extern "C" void kernel_launch(void* const* d_in, const int* in_sizes, int n_in,
                              void* d_out, int out_size, void* d_ws, size_t ws_size,
                              hipStream_t stream) {
  (void)in_sizes; (void)n_in; (void)out_size; (void)ws_size;
  const float* hidden = (const float*)d_in[0];
  const float* ln1_g = (const float*)d_in[1];
  const float* ln1_b = (const float*)d_in[2];
  const float* w_qkv = (const float*)d_in[3];
  const float* b_qkv = (const float*)d_in[4];
  const float* apv = (const float*)d_in[5];
  const float* apg = (const float*)d_in[6];
  const float* apb = (const float*)d_in[7];
  // d_in[8] emotion_bias: softmax-invariant -> dropped (exact)
  const float* ln2_g = (const float*)d_in[9];
  const float* ln2_b = (const float*)d_in[10];
  const float* w_fc = (const float*)d_in[11];
  const float* b_fc = (const float*)d_in[12];
  const float* mpv = (const float*)d_in[13];
  const float* mpg = (const float*)d_in[14];
  const float* mpb = (const float*)d_in[15];

  char* w = (char*)d_ws;
  const size_t MBs = 1ull << 20;
  float* hidden2 = (float*)(w + 0);                           // 32 MiB (live G2..end)
  unsigned short* vbuf = (unsigned short*)(w + 32 * MBs);     // 16 MiB (G1..vtrans)
  unsigned short* vtbuf = (unsigned short*)(w + 48 * MBs);    // 16 MiB (vtrans..attn)
  unsigned short* hbuf = (unsigned short*)(w + 32 * MBs);     // 64 MiB (G3..G4, after attn)
  unsigned short* qbuf = (unsigned short*)(w + 96 * MBs);     // 16 MiB
  unsigned short* kbuf = (unsigned short*)(w + 112 * MBs);    // 16 MiB
  unsigned short* xln = (unsigned short*)(w + 128 * MBs);     // 16 MiB (xln -> attn_out)
  unsigned short* xln2 = (unsigned short*)(w + 144 * MBs);    // 16 MiB
  unsigned short* wqkv_bf = (unsigned short*)(w + 160 * MBs); // 24 MiB (dead after G1)
  unsigned short* w2_bf = (unsigned short*)(w + 160 * MBs);   // 32 MiB (after G1)
  unsigned short* wproj_bf = (unsigned short*)(w + 192 * MBs);// 8 MiB
  float* s_attn = (float*)(w + 200 * MBs);                    // 8 KiB
  float* s_mlp = (float*)(w + 200 * MBs + 32768);             // 32 KiB
  unsigned short* wfc_bf = qbuf;   // 32 MiB over dead q+k (after attn)

  hipFuncSetAttribute((const void*)g1_qkv8p, hipFuncAttributeMaxDynamicSharedMemorySize, 131072);
  hipFuncSetAttribute((const void*)g3a_fc8p, hipFuncAttributeMaxDynamicSharedMemorySize, 131072);
  hipFuncSetAttribute((const void*)g3b_fc2p, hipFuncAttributeMaxDynamicSharedMemorySize, 65536);

  // weight prep
  cast_k<<<2048, 256, 0, stream>>>(w_qkv, wqkv_bf, (6144 * 2048) / 4);
  colnorm_k<<<32, 256, 0, stream>>>(apv, apg, s_attn, 2048, 2048);
  scale_cast_k<<<2048, 256, 0, stream>>>(apv, s_attn, wproj_bf, 2048, (2048 * 2048) / 4);
  colnorm_k<<<128, 256, 0, stream>>>(mpv, mpg, s_mlp, 2048, 8192);

  // LN1 -> xln (bf16)
  ln_k<<<4096, 256, 0, stream>>>(hidden, ln1_g, ln1_b, xln);

  // GEMM1 (8-phase 256^2 + 2D XCD chunk): qkv -> q/k/v [B,H,S,D]
  GemmP p1 = {xln, wqkv_bf, b_qkv, nullptr, nullptr, nullptr,
              qbuf, kbuf, vbuf, 4096, 6144, 2048};
  g1_qkv8p<<<384, 512, 131072, stream>>>(p1);

  // V -> V^T
  vtrans_k<<<1024, 256, 0, stream>>>(vbuf, vtbuf);

  // attention -> attn_out (xln slot)
  attn_k<<<1024, 256, 0, stream>>>(qbuf, kbuf, vtbuf, xln);

  // weight casts for MLP (into regions dead after GEMM1/attn)
  cast_k<<<2048, 256, 0, stream>>>(w_fc, wfc_bf, (8192 * 2048) / 4);
  scale_cast_k<<<4096, 256, 0, stream>>>(mpv, s_mlp, w2_bf, 8192, (2048 * 8192) / 4);

  // GEMM2 (128^2 + chunk): hidden2 = attn_out @ w_proj^T + b + hidden
  GemmP p2 = {xln, wproj_bf, apb, hidden, hidden2, nullptr,
              nullptr, nullptr, nullptr, 4096, 2048, 2048};
  g2_proj128<<<512, 256, 0, stream>>>(p2);

  // LN2 -> xln2
  ln_k<<<4096, 256, 0, stream>>>(hidden2, ln2_g, ln2_b, xln2);

  // GEMM3 A/B experiment: rows 0-2047 via 8-phase, rows 2048-4095 via 2-phase
  GemmP p3 = {xln2, wfc_bf, b_fc, nullptr, nullptr, hbuf,
              nullptr, nullptr, nullptr, 4096, 8192, 2048};
  g3a_fc8p<<<256, 512, 131072, stream>>>(p3);
  g3b_fc2p<<<256, 512, 65536, stream>>>(p3);

  // GEMM4 (128^2 + chunk): out = h @ w2^T + b + hidden2 (fp32)
  GemmP p4 = {hbuf, w2_bf, mpb, hidden2, (float*)d_out, nullptr,
              nullptr, nullptr, nullptr, 4096, 2048, 8192};
  g4_out128<<<512, 256, 0, stream>>>(p4);
}

// Round 5
// 1257.585 us; speedup vs baseline: 1.0179x; 1.0179x over previous
//
#include <hip/hip_runtime.h>
#include <hip/hip_bf16.h>

#define DEVI __device__ __forceinline__

typedef __attribute__((ext_vector_type(8))) __bf16 bf16x8;
typedef __attribute__((ext_vector_type(4))) float f32x4;
typedef __attribute__((ext_vector_type(4))) unsigned short u16x4;
typedef __attribute__((ext_vector_type(8))) unsigned short u16x8;

DEVI unsigned short f2bf(float f) {
  unsigned int u = __float_as_uint(f);
  u += 0x7FFFu + ((u >> 16) & 1u);   // RNE
  return (unsigned short)(u >> 16);
}

#define GLD16(g, l) __builtin_amdgcn_global_load_lds(                      \
    (const __attribute__((address_space(1))) void*)(g),                    \
    (__attribute__((address_space(3))) void*)(l), 16, 0, 0)

// ---------------------------------------------------------------- helpers

__global__ __launch_bounds__(256) void cast_k(const float* __restrict__ in,
                                              unsigned short* __restrict__ out,
                                              int n4) {
  for (int i = blockIdx.x * 256 + threadIdx.x; i < n4; i += gridDim.x * 256) {
    f32x4 v = ((const f32x4*)in)[i];
    u16x4 o;
    o.x = f2bf(v.x); o.y = f2bf(v.y); o.z = f2bf(v.z); o.w = f2bf(v.w);
    ((u16x4*)out)[i] = o;
  }
}

__global__ __launch_bounds__(256) void colnorm_k(const float* __restrict__ v,
                                                 const float* __restrict__ g,
                                                 float* __restrict__ s,
                                                 int rows, int cols) {
  const int tid = threadIdx.x;
  const int c0 = blockIdx.x * 64;
  const int c = tid & 63, rg = tid >> 6;
  float acc = 0.f;
  for (int i = rg; i < rows; i += 4) {
    float x = v[(size_t)i * cols + c0 + c];
    acc += x * x;
  }
  __shared__ float red[256];
  red[tid] = acc;
  __syncthreads();
  if (tid < 64) {
    float t = red[tid] + red[tid + 64] + red[tid + 128] + red[tid + 192];
    s[c0 + tid] = g[c0 + tid] * rsqrtf(t);
  }
}

__global__ __launch_bounds__(256) void scale_cast_k(const float* __restrict__ in,
                                                    const float* __restrict__ s,
                                                    unsigned short* __restrict__ out,
                                                    int cols, int n4) {
  const int cmask4 = (cols >> 2) - 1;
  for (int i = blockIdx.x * 256 + threadIdx.x; i < n4; i += gridDim.x * 256) {
    f32x4 v = ((const f32x4*)in)[i];
    f32x4 sv = ((const f32x4*)s)[i & cmask4];
    u16x4 o;
    o.x = f2bf(v.x * sv.x); o.y = f2bf(v.y * sv.y);
    o.z = f2bf(v.z * sv.z); o.w = f2bf(v.w * sv.w);
    ((u16x4*)out)[i] = o;
  }
}

// LayerNorm: one block per row of 2048 fp32, out bf16
__global__ __launch_bounds__(256) void ln_k(const float* __restrict__ x,
                                            const float* __restrict__ g,
                                            const float* __restrict__ b,
                                            unsigned short* __restrict__ out) {
  const int tid = threadIdx.x, lane = tid & 63, wid = tid >> 6;
  const int row = blockIdx.x;
  const float* xr = x + (size_t)row * 2048;
  f32x4 a0 = ((const f32x4*)xr)[tid];
  f32x4 a1 = ((const f32x4*)xr)[tid + 256];
  float s = a0.x + a0.y + a0.z + a0.w + a1.x + a1.y + a1.z + a1.w;
  float ss = a0.x * a0.x + a0.y * a0.y + a0.z * a0.z + a0.w * a0.w +
             a1.x * a1.x + a1.y * a1.y + a1.z * a1.z + a1.w * a1.w;
#pragma unroll
  for (int m = 1; m < 64; m <<= 1) {
    s += __shfl_xor(s, m);
    ss += __shfl_xor(ss, m);
  }
  __shared__ float red[8];
  if (lane == 0) { red[wid] = s; red[4 + wid] = ss; }
  __syncthreads();
  s = red[0] + red[1] + red[2] + red[3];
  ss = red[4] + red[5] + red[6] + red[7];
  const float mu = s * (1.f / 2048.f);
  const float var = ss * (1.f / 2048.f) - mu * mu;
  const float rs = rsqrtf(var + 1e-5f);
  f32x4 g0 = ((const f32x4*)g)[tid], g1 = ((const f32x4*)g)[tid + 256];
  f32x4 b0 = ((const f32x4*)b)[tid], b1 = ((const f32x4*)b)[tid + 256];
  u16x4 o0, o1;
  o0.x = f2bf((a0.x - mu) * rs * g0.x + b0.x);
  o0.y = f2bf((a0.y - mu) * rs * g0.y + b0.y);
  o0.z = f2bf((a0.z - mu) * rs * g0.z + b0.z);
  o0.w = f2bf((a0.w - mu) * rs * g0.w + b0.w);
  o1.x = f2bf((a1.x - mu) * rs * g1.x + b1.x);
  o1.y = f2bf((a1.y - mu) * rs * g1.y + b1.y);
  o1.z = f2bf((a1.z - mu) * rs * g1.z + b1.z);
  o1.w = f2bf((a1.w - mu) * rs * g1.w + b1.w);
  unsigned short* orow = out + (size_t)row * 2048;
  *(u16x4*)(orow + 4 * tid) = o0;
  *(u16x4*)(orow + 1024 + 4 * tid) = o1;
}

// V transpose: v [32][2048][128] -> vt [32][128][2048]
__global__ __launch_bounds__(256) void vtrans_k(const unsigned short* __restrict__ v,
                                                unsigned short* __restrict__ vt) {
  __shared__ unsigned short t[64][134];
  const int tid = threadIdx.x;
  const int bh = blockIdx.x >> 5, st = blockIdx.x & 31;
  const unsigned short* vb = v + ((size_t)bh << 18) + ((size_t)(st << 6) << 7);
#pragma unroll
  for (int i = 0; i < 4; ++i) {
    int f = tid + (i << 8);
    int row = f >> 4, c8 = f & 15;
    u16x8 x = *(const u16x8*)(vb + row * 128 + c8 * 8);
#pragma unroll
    for (int j = 0; j < 4; ++j) {
      unsigned int pk = ((unsigned int)x[2 * j + 1] << 16) | x[2 * j];
      *(unsigned int*)&t[row][c8 * 8 + 2 * j] = pk;
    }
  }
  __syncthreads();
  const int lane = tid & 63, wid = tid >> 6;
  unsigned short* ob = vt + ((size_t)bh << 18) + (st << 6);
#pragma unroll
  for (int j = 0; j < 32; ++j) {
    int d = (wid << 5) + j;
    ob[((size_t)d << 11) + lane] = t[lane][d];
  }
}

// split-K reduce: out = part0 + part1 + bias + res  (all fp32, N=2048 rows)
__global__ __launch_bounds__(256) void g4red_k(const float* __restrict__ p0,
                                               const float* __restrict__ p1,
                                               const float* __restrict__ bias,
                                               const float* __restrict__ res,
                                               float* __restrict__ out, int n4) {
  for (int i = blockIdx.x * 256 + threadIdx.x; i < n4; i += gridDim.x * 256) {
    f32x4 a = ((const f32x4*)p0)[i];
    f32x4 b = ((const f32x4*)p1)[i];
    f32x4 r = ((const f32x4*)res)[i];
    f32x4 bb = ((const f32x4*)bias)[i & 511];   // 2048/4 - 1
    f32x4 o;
    o.x = a.x + b.x + r.x + bb.x;
    o.y = a.y + b.y + r.y + bb.y;
    o.z = a.z + b.z + r.z + bb.z;
    o.w = a.w + b.w + r.w + bb.w;
    ((f32x4*)out)[i] = o;
  }
}

// ---------------------------------------------------------------- GEMM params
struct GemmP {
  const unsigned short* A;
  const unsigned short* B;
  const float* bias;
  const float* res;
  float* outF;
  unsigned short* outH;
  unsigned short* q;
  unsigned short* k;
  unsigned short* vt;   // EPI0: v (row-major [B,H,S,D])
  int M, N, K;
};

// ---------------------------------------------------------------- 128^2 GEMM (2-phase)
// EPI: 0 = +bias scatter q/k/v  1 = +bias+res -> fp32  4 = raw partial -> fp32
template <int EPI>
DEVI void gemm128_body(const GemmP& p, int m0, int n0, int k0, int nk) {
  const int tid = threadIdx.x, lane = tid & 63, wid = tid >> 6;
  const int K = p.K;
  const int wr = wid >> 1, wc = wid & 1;

  __shared__ __align__(16) unsigned short sA[2][4096];
  __shared__ __align__(16) unsigned short sB[2][4096];

  const int c0 = tid, c1 = tid + 256;
  const unsigned short* gA0 = p.A + (size_t)(m0 + (c0 >> 2)) * K + k0 + ((c0 & 3) << 3);
  const unsigned short* gA1 = p.A + (size_t)(m0 + (c1 >> 2)) * K + k0 + ((c1 & 3) << 3);
  const unsigned short* gB0 = p.B + (size_t)(n0 + (c0 >> 2)) * K + k0 + ((c0 & 3) << 3);
  const unsigned short* gB1 = p.B + (size_t)(n0 + (c1 >> 2)) * K + k0 + ((c1 & 3) << 3);
  const int l0 = wid << 9, l1 = (wid << 9) + 2048;

  f32x4 acc[4][4] = {};
  const int arow = (wr << 6) + (lane & 15);
  const int brow = (wc << 6) + (lane & 15);
  const int koff = (lane >> 4) << 3;

#define STAGE128(bufi, t) do { int ko = (t) << 5;       \
    GLD16(gA0 + ko, &sA[bufi][l0]);                     \
    GLD16(gA1 + ko, &sA[bufi][l1]);                     \
    GLD16(gB0 + ko, &sB[bufi][l0]);                     \
    GLD16(gB1 + ko, &sB[bufi][l1]); } while (0)

  STAGE128(0, 0);
  __syncthreads();
  int cur = 0;
  for (int t = 0; t < nk; ++t) {
    if (t + 1 < nk) STAGE128(cur ^ 1, t + 1);
    bf16x8 af[4], bfr[4];
#pragma unroll
    for (int i = 0; i < 4; ++i)
      af[i] = *(const bf16x8*)&sA[cur][(arow + (i << 4)) * 32 + koff];
#pragma unroll
    for (int i = 0; i < 4; ++i)
      bfr[i] = *(const bf16x8*)&sB[cur][(brow + (i << 4)) * 32 + koff];
#pragma unroll
    for (int i = 0; i < 4; ++i)
#pragma unroll
      for (int j = 0; j < 4; ++j)
        acc[i][j] = __builtin_amdgcn_mfma_f32_16x16x32_bf16(af[i], bfr[j], acc[i][j], 0, 0, 0);
    __syncthreads();
    cur ^= 1;
  }
#undef STAGE128

  const int rbase = m0 + (wr << 6) + ((lane >> 4) << 2);
  const int cbase = n0 + (wc << 6) + (lane & 15);
#pragma unroll
  for (int mi = 0; mi < 4; ++mi) {
#pragma unroll
    for (int ni = 0; ni < 4; ++ni) {
      const int col = cbase + (ni << 4);
#pragma unroll
      for (int r = 0; r < 4; ++r) {
        const int row = rbase + (mi << 4) + r;
        if constexpr (EPI == 0) {
          float v = acc[mi][ni][r] + p.bias[col];
          const int gsel = col >> 11, e = col & 2047;
          const int h = e >> 7, d = e & 127;
          const int b2 = row >> 11, sidx = row & 2047;
          const size_t off = ((size_t)(b2 * 16 + h) << 18) + ((size_t)sidx << 7) + d;
          unsigned short hv = f2bf(v);
          if (gsel == 0)      p.q[off] = hv;
          else if (gsel == 1) p.k[off] = hv;
          else                p.vt[off] = hv;   // v row-major; transposed later
        } else if constexpr (EPI == 1) {
          const size_t o = (size_t)row * p.N + col;
          p.outF[o] = acc[mi][ni][r] + p.bias[col] + p.res[o];
        } else {
          p.outF[(size_t)row * p.N + col] = acc[mi][ni][r];   // raw partial
        }
      }
    }
  }
}

// G1: M=4096,N=6144 -> nbm=32,nbn=48. Region/XCD = 32 rows x 6 cols, bm-fastest.
__global__ __launch_bounds__(256) void g1_qkv128(GemmP p) {
  const int x = blockIdx.x & 7, i = blockIdx.x >> 3;  // i in [0,192)
  const int bm = i & 31;
  const int bn = x * 6 + (i >> 5);
  gemm128_body<0>(p, bm << 7, bn << 7, 0, p.K >> 5);
}
// G2: M=4096,N=2048 -> nbm=32,nbn=16. Region/XCD = 8x8.
__global__ __launch_bounds__(256) void g2_proj128(GemmP p) {
  const int x = blockIdx.x & 7, i = blockIdx.x >> 3;  // i in [0,64)
  const int bm = (x >> 1) * 8 + (i >> 3);
  const int bn = (x & 1) * 8 + (i & 7);
  gemm128_body<1>(p, bm << 7, bn << 7, 0, p.K >> 5);
}
// G4 split-K: 1024 blocks; tile (bm,bn) x K-half ks; partial -> p.outF (+ks offset)
__global__ __launch_bounds__(256) void g4_splitk(GemmP p) {
  const int x = blockIdx.x & 7, i = blockIdx.x >> 3;  // i in [0,128)
  const int ks = i & 1, j = i >> 1;                   // j in [0,64)
  const int bm = (x >> 1) * 8 + (j >> 3);
  const int bn = (x & 1) * 8 + (j & 7);
  GemmP q = p;
  q.outF = p.outF + (size_t)ks * 4096 * 2048;
  gemm128_body<4>(q, bm << 7, bn << 7, ks << 12, 128);   // K-half = 4096 = 128 steps
}

// ---------------------------------------------------------------- 256^2 tile common
DEVI void setup256(const GemmP& p, int m0, int n0,
                   const unsigned short*& gsA0, const unsigned short*& gsA1,
                   const unsigned short*& gsB0, const unsigned short*& gsB1) {
  const int tid = threadIdx.x;
  int r_[2], c_[2];
#pragma unroll
  for (int j = 0; j < 2; ++j) {
    int d = tid * 16 + j * 8192;
    int w = (d & 1023) ^ (((d >> 9) & 1) << 5);   // st_16x32 involution
    r_[j] = ((d >> 10) << 4) + (w >> 6);
    c_[j] = (w & 63) >> 1;
  }
  gsA0 = p.A + (size_t)(m0 + r_[0]) * p.K + c_[0];
  gsA1 = p.A + (size_t)(m0 + r_[1]) * p.K + c_[1];
  gsB0 = p.B + (size_t)(n0 + r_[0]) * p.K + c_[0];
  gsB1 = p.B + (size_t)(n0 + r_[1]) * p.K + c_[1];
}

// epilogue: +bias, fast-GELU -> bf16
DEVI void epi256g(const GemmP& p, f32x4 (&acc)[8][4], int m0, int n0) {
  const int lane = threadIdx.x & 63, wid = threadIdx.x >> 6;
  const int wr = wid >> 2, wc = wid & 3;
  const int lr = lane & 15, lk = lane >> 4;
  const int rbase = m0 + wr * 128 + (lk << 2);
  const int cbase = n0 + wc * 64 + lr;
#pragma unroll
  for (int m = 0; m < 8; ++m) {
#pragma unroll
    for (int n = 0; n < 4; ++n) {
      const int col = cbase + (n << 4);
      const float bb = p.bias[col];
#pragma unroll
      for (int r = 0; r < 4; ++r) {
        const int row = rbase + (m << 4) + r;
        float v = acc[m][n][r] + bb;
        float y = 0.7978845608028654f * (v + 0.044715f * v * v * v);
        float u = __expf(2.f * y);
        float gl = (y > 40.f) ? v : v * (u / (u + 1.f));
        p.outH[(size_t)row * p.N + col] = f2bf(gl);
      }
    }
  }
}

// ---------------------------------------------------------------- 256^2 8-phase (A arm)
DEVI void gemm8p_body(const GemmP& p, unsigned short* lds_raw, int m0, int n0) {
  const int tid = threadIdx.x, lane = tid & 63, wid = tid >> 6;
  const int wr = wid >> 2, wc = wid & 3;
  const int lr = lane & 15, lk = lane >> 4;
  const int fb = (lr * 64 + lk * 16) ^ ((lr & 8) << 2);

  const unsigned short *gsA0, *gsA1, *gsB0, *gsB1;
  setup256(p, m0, n0, gsA0, gsA1, gsB0, gsB1);

#define STAGE_A8(b, kt) do { unsigned short* _d = lds_raw + ((b) << 14);       \
    GLD16(gsA0 + ((size_t)(kt) << 5), _d + (tid << 3));                        \
    GLD16(gsA1 + ((size_t)(kt) << 5), _d + 4096 + (tid << 3)); } while (0)
#define STAGE_B8(b, kt) do { unsigned short* _d = lds_raw + ((b) << 14) + 8192;\
    GLD16(gsB0 + ((size_t)(kt) << 5), _d + (tid << 3));                        \
    GLD16(gsB1 + ((size_t)(kt) << 5), _d + 4096 + (tid << 3)); } while (0)

  f32x4 acc[8][4] = {};
  const int NK = p.K >> 5;

  STAGE_A8(0, 0); STAGE_B8(0, 0);
  STAGE_A8(1, 1); STAGE_B8(1, 1);
  STAGE_A8(2, 2); STAGE_B8(2, 2);
  asm volatile("s_waitcnt vmcnt(8)" ::: "memory");
  __builtin_amdgcn_s_barrier();

  for (int t = 0; t < NK; ++t) {
    const int bi = t & 3;
    const char* tA = (const char*)(lds_raw + (bi << 14));
    const char* tB = (const char*)(lds_raw + (bi << 14) + 8192);
    bf16x8 a_[4], b_[4];
#pragma unroll
    for (int n = 0; n < 4; ++n)
      b_[n] = *(const bf16x8*)(tB + (((wc << 2) + n) << 10) + fb);
#pragma unroll
    for (int m = 0; m < 4; ++m)
      a_[m] = *(const bf16x8*)(tA + (((wr << 3) + m) << 10) + fb);
    if (t + 3 < NK) STAGE_A8((t + 3) & 3, t + 3);
    __builtin_amdgcn_s_barrier();
    asm volatile("s_waitcnt lgkmcnt(0)" ::: "memory");
    __builtin_amdgcn_sched_barrier(0);
    __builtin_amdgcn_s_setprio(1);
#pragma unroll
    for (int m = 0; m < 4; ++m)
#pragma unroll
      for (int n = 0; n < 4; ++n)
        acc[m][n] = __builtin_amdgcn_mfma_f32_16x16x32_bf16(a_[m], b_[n], acc[m][n], 0, 0, 0);
    __builtin_amdgcn_s_setprio(0);
    __builtin_amdgcn_s_barrier();
#pragma unroll
    for (int m = 0; m < 4; ++m)
      a_[m] = *(const bf16x8*)(tA + (((wr << 3) + 4 + m) << 10) + fb);
    if (t + 3 < NK) STAGE_B8((t + 3) & 3, t + 3);
    if (t + 3 < NK)      asm volatile("s_waitcnt vmcnt(8)" ::: "memory");
    else if (t + 2 < NK) asm volatile("s_waitcnt vmcnt(4)" ::: "memory");
    else if (t + 1 < NK) asm volatile("s_waitcnt vmcnt(0)" ::: "memory");
    __builtin_amdgcn_s_barrier();
    asm volatile("s_waitcnt lgkmcnt(0)" ::: "memory");
    __builtin_amdgcn_sched_barrier(0);
    __builtin_amdgcn_s_setprio(1);
#pragma unroll
    for (int m = 0; m < 4; ++m)
#pragma unroll
      for (int n = 0; n < 4; ++n)
        acc[4 + m][n] = __builtin_amdgcn_mfma_f32_16x16x32_bf16(a_[m], b_[n], acc[4 + m][n], 0, 0, 0);
    __builtin_amdgcn_s_setprio(0);
    __builtin_amdgcn_s_barrier();
  }
#undef STAGE_A8
#undef STAGE_B8
  epi256g(p, acc, m0, n0);
}

// ---------------------------------------------------------------- 256^2 2-phase (B arm)
DEVI void gemm2p_body(const GemmP& p, unsigned short* lds_raw, int m0, int n0) {
  const int tid = threadIdx.x, lane = tid & 63, wid = tid >> 6;
  const int wr = wid >> 2, wc = wid & 3;
  const int lr = lane & 15, lk = lane >> 4;
  const int fb = (lr * 64 + lk * 16) ^ ((lr & 8) << 2);

  const unsigned short *gsA0, *gsA1, *gsB0, *gsB1;
  setup256(p, m0, n0, gsA0, gsA1, gsB0, gsB1);

#define STG2(b, kt) do { unsigned short* _d = lds_raw + ((b) << 14);     \
    GLD16(gsA0 + ((size_t)(kt) << 5), _d + (tid << 3));                  \
    GLD16(gsA1 + ((size_t)(kt) << 5), _d + 4096 + (tid << 3));           \
    GLD16(gsB0 + ((size_t)(kt) << 5), _d + 8192 + (tid << 3));           \
    GLD16(gsB1 + ((size_t)(kt) << 5), _d + 12288 + (tid << 3)); } while (0)

  f32x4 acc[8][4] = {};
  const int NK = p.K >> 5;
  STG2(0, 0);
  __syncthreads();
  int cur = 0;
  for (int t = 0; t < NK; ++t) {
    if (t + 1 < NK) STG2(cur ^ 1, t + 1);
    const char* tA = (const char*)(lds_raw + (cur << 14));
    const char* tB = tA + 16384;
    bf16x8 a_[8], b_[4];
#pragma unroll
    for (int n = 0; n < 4; ++n)
      b_[n] = *(const bf16x8*)(tB + (((wc << 2) + n) << 10) + fb);
#pragma unroll
    for (int m = 0; m < 8; ++m)
      a_[m] = *(const bf16x8*)(tA + (((wr << 3) + m) << 10) + fb);
#pragma unroll
    for (int m = 0; m < 8; ++m)
#pragma unroll
      for (int n = 0; n < 4; ++n)
        acc[m][n] = __builtin_amdgcn_mfma_f32_16x16x32_bf16(a_[m], b_[n], acc[m][n], 0, 0, 0);
    __syncthreads();
    cur ^= 1;
  }
#undef STG2
  epi256g(p, acc, m0, n0);
}

// G3a: rows [0,2048), 8-phase. nbm=8,nbn=32; region 4x8 per XCD
__global__ __launch_bounds__(512, 2) void g3a_fc8p(GemmP p) {
  extern __shared__ unsigned short lds_raw[];
  const int x = blockIdx.x & 7, i = blockIdx.x >> 3;
  const int bm = (x >> 2) * 4 + (i >> 3);
  const int bn = (x & 3) * 8 + (i & 7);
  gemm8p_body(p, lds_raw, bm << 8, bn << 8);
}
// G3b: rows [2048,4096), 2-phase (A/B control)
__global__ __launch_bounds__(512, 2) void g3b_fc2p(GemmP p) {
  extern __shared__ unsigned short lds_raw[];
  const int x = blockIdx.x & 7, i = blockIdx.x >> 3;
  const int bm = (x >> 2) * 4 + (i >> 3);
  const int bn = (x & 3) * 8 + (i & 7);
  gemm2p_body(p, lds_raw, 2048 + (bm << 8), bn << 8);
}

// ---------------------------------------------------------------- attention
// Q,K in [B,H,S,D]; V^T in [B,H,D,S]; O bf16 [4096,2048].
// Reg-staged K/V prefetch (T14) + defer-max (T13) + setprio on MFMA (T5).
__global__ __launch_bounds__(256) void attn_k(const unsigned short* __restrict__ Q,
                                              const unsigned short* __restrict__ Kg,
                                              const unsigned short* __restrict__ Vt,
                                              unsigned short* __restrict__ O) {
  const int tid = threadIdx.x, lane = tid & 63, wid = tid >> 6;
  const int bid = blockIdx.x;
  const int pos = bid >> 3;
  const int bh = (bid & 7) * 4 + (pos >> 5);
  const int qt = pos & 31;
  const int q0 = qt * 64 + wid * 16;
  const int b = bh >> 4, h = bh & 15;

  __shared__ __align__(16) unsigned short sK[64 * 128];
  __shared__ __align__(16) unsigned short sV[128 * 64];
  __shared__ __align__(16) unsigned short sP[4][16 * 72];

  const unsigned short* Qb = Q + ((size_t)bh << 18);
  const unsigned short* Kb = Kg + ((size_t)bh << 18);
  const unsigned short* Vb = Vt + ((size_t)bh << 18);

  bf16x8 qf[4];
  {
    const unsigned short* qp = Qb + (size_t)(q0 + (lane & 15)) * 128 + ((lane >> 4) << 3);
#pragma unroll
    for (int kk = 0; kk < 4; ++kk) qf[kk] = *(const bf16x8*)(qp + kk * 32);
  }

  int koffs[4], voffs[4];
#pragma unroll
  for (int i = 0; i < 4; ++i) {
    const int c = tid + (i << 8);
    const int kv = c >> 4, jj = c & 15;
    const int js = (jj & 8) | ((jj ^ kv) & 7);
    koffs[i] = kv * 128 + (js << 3);
    const int d = c >> 3, j2 = c & 7;
    const int js2 = j2 ^ (d & 7);
    voffs[i] = d * 2048 + (js2 << 3);
  }
  u16x8 kreg[4], vreg[4];
  auto PREF = [&](int kt) {
    const int kv0 = kt << 6;
#pragma unroll
    for (int i = 0; i < 4; ++i) {
      kreg[i] = *(const u16x8*)(Kb + kv0 * 128 + koffs[i]);
      vreg[i] = *(const u16x8*)(Vb + kv0 + voffs[i]);
    }
  };

  f32x4 oacc[8] = {};
  float mrun = -3e38f, lrun = 0.f;
  PREF(0);

  for (int kt = 0; kt < 32; ++kt) {
#pragma unroll
    for (int i = 0; i < 4; ++i) {
      const int c8 = (tid + (i << 8)) << 3;
      *(u16x8*)&sK[c8] = kreg[i];
      *(u16x8*)&sV[c8] = vreg[i];
    }
    __syncthreads();
    if (kt + 1 < 32) PREF(kt + 1);

    f32x4 sc[4] = {};
    __builtin_amdgcn_s_setprio(1);
#pragma unroll
    for (int ti = 0; ti < 4; ++ti) {
#pragma unroll
      for (int kk = 0; kk < 4; ++kk) {
        const int row = (ti << 4) + (lane & 15);
        int bo = (row << 8) + (kk << 6) + ((lane >> 4) << 4);
        bo ^= (row & 7) << 4;
        bf16x8 kf = *(const bf16x8*)((const char*)sK + bo);
        sc[ti] = __builtin_amdgcn_mfma_f32_16x16x32_bf16(kf, qf[kk], sc[ti], 0, 0, 0);
      }
    }
    __builtin_amdgcn_s_setprio(0);

    float pv[16];
    float mx = -3e38f;
#pragma unroll
    for (int ti = 0; ti < 4; ++ti)
#pragma unroll
      for (int r = 0; r < 4; ++r) {
        float x = sc[ti][r] * 0.08838834764831845f;
        pv[(ti << 2) + r] = x;
        mx = fmaxf(mx, x);
      }
    mx = fmaxf(mx, __shfl_xor(mx, 16));
    mx = fmaxf(mx, __shfl_xor(mx, 32));

    float corr = 1.f;
    if (!__all(mx - mrun <= 8.f)) {
      const float mnew = fmaxf(mrun, mx);
      corr = __expf(mrun - mnew);
      mrun = mnew;
      float fr[4];
#pragma unroll
      for (int r = 0; r < 4; ++r) fr[r] = __shfl(corr, ((lane >> 4) << 2) + r);
#pragma unroll
      for (int di = 0; di < 8; ++di)
#pragma unroll
        for (int r = 0; r < 4; ++r) oacc[di][r] *= fr[r];
    }
    float psum = 0.f;
#pragma unroll
    for (int i2 = 0; i2 < 16; ++i2) {
      float e = __expf(pv[i2] - mrun);
      pv[i2] = e;
      psum += e;
    }
    psum += __shfl_xor(psum, 16);
    psum += __shfl_xor(psum, 32);
    lrun = lrun * corr + psum;

    unsigned short* prow = &sP[wid][(lane & 15) * 72];
#pragma unroll
    for (int ti = 0; ti < 4; ++ti) {
      u16x4 w4;
      w4.x = f2bf(pv[(ti << 2) + 0]);
      w4.y = f2bf(pv[(ti << 2) + 1]);
      w4.z = f2bf(pv[(ti << 2) + 2]);
      w4.w = f2bf(pv[(ti << 2) + 3]);
      *(u16x4*)&prow[(ti << 4) + ((lane >> 4) << 2)] = w4;
    }

    __builtin_amdgcn_s_setprio(1);
#pragma unroll
    for (int di = 0; di < 8; ++di) {
#pragma unroll
      for (int ks = 0; ks < 2; ++ks) {
        bf16x8 pf = *(const bf16x8*)((const char*)&sP[wid][0] +
                                     (lane & 15) * 144 + (ks << 6) + ((lane >> 4) << 4));
        const int dr = (di << 4) + (lane & 15);
        int bo = (dr << 7) + (ks << 6) + ((lane >> 4) << 4);
        bo ^= (dr & 7) << 4;
        bf16x8 vf = *(const bf16x8*)((const char*)sV + bo);
        oacc[di] = __builtin_amdgcn_mfma_f32_16x16x32_bf16(pf, vf, oacc[di], 0, 0, 0);
      }
    }
    __builtin_amdgcn_s_setprio(0);
    __syncthreads();
  }

  float il[4];
#pragma unroll
  for (int r = 0; r < 4; ++r) il[r] = 1.f / __shfl(lrun, ((lane >> 4) << 2) + r);
  const size_t obase = ((size_t)(b * 2048 + q0)) * 2048 + h * 128;
#pragma unroll
  for (int di = 0; di < 8; ++di)
#pragma unroll
    for (int r = 0; r < 4; ++r) {
      const size_t o = obase + (size_t)(((lane >> 4) << 2) + r) * 2048 + (di << 4) + (lane & 15);
      O[o] = f2bf(oacc[di][r] * il[r]);
    }
}

// ---------------------------------------------------------------- launch

extern "C" void kernel_launch(void* const* d_in, const int* in_sizes, int n_in,
                              void* d_out, int out_size, void* d_ws, size_t ws_size,
                              hipStream_t stream) {
  (void)in_sizes; (void)n_in; (void)out_size; (void)ws_size;
  const float* hidden = (const float*)d_in[0];
  const float* ln1_g = (const float*)d_in[1];
  const float* ln1_b = (const float*)d_in[2];
  const float* w_qkv = (const float*)d_in[3];
  const float* b_qkv = (const float*)d_in[4];
  const float* apv = (const float*)d_in[5];
  const float* apg = (const float*)d_in[6];
  const float* apb = (const float*)d_in[7];
  // d_in[8] emotion_bias: softmax-invariant -> dropped (exact)
  const float* ln2_g = (const float*)d_in[9];
  const float* ln2_b = (const float*)d_in[10];
  const float* w_fc = (const float*)d_in[11];
  const float* b_fc = (const float*)d_in[12];
  const float* mpv = (const float*)d_in[13];
  const float* mpg = (const float*)d_in[14];
  const float* mpb = (const float*)d_in[15];

  char* w = (char*)d_ws;
  const size_t MBs = 1ull << 20;
  float* hidden2 = (float*)(w + 0);                           // 32 MiB (live G2..end)
  unsigned short* vbuf = (unsigned short*)(w + 32 * MBs);     // 16 MiB (G1..vtrans)
  unsigned short* vtbuf = (unsigned short*)(w + 48 * MBs);    // 16 MiB (vtrans..attn)
  unsigned short* hbuf = (unsigned short*)(w + 32 * MBs);     // 64 MiB (G3..G4, after attn)
  unsigned short* qbuf = (unsigned short*)(w + 96 * MBs);     // 16 MiB
  unsigned short* kbuf = (unsigned short*)(w + 112 * MBs);    // 16 MiB
  unsigned short* xln = (unsigned short*)(w + 128 * MBs);     // 16 MiB (xln -> attn_out)
  unsigned short* xln2 = (unsigned short*)(w + 144 * MBs);    // 16 MiB
  unsigned short* wqkv_bf = (unsigned short*)(w + 160 * MBs); // 24 MiB (dead after G1)
  unsigned short* w2_bf = (unsigned short*)(w + 160 * MBs);   // 32 MiB (after G1)
  unsigned short* wproj_bf = (unsigned short*)(w + 192 * MBs);// 8 MiB
  float* s_attn = (float*)(w + 200 * MBs);                    // 8 KiB
  float* s_mlp = (float*)(w + 200 * MBs + 32768);             // 32 KiB
  unsigned short* wfc_bf = qbuf;        // 32 MiB over dead q+k (after attn)
  float* part0 = (float*)(w + 96 * MBs);   // 32 MiB over dead qbuf/kbuf (at G4)
  float* part1 = (float*)(w + 128 * MBs);  // 32 MiB over dead xln/xln2 (at G4)

  hipFuncSetAttribute((const void*)g3a_fc8p, hipFuncAttributeMaxDynamicSharedMemorySize, 131072);
  hipFuncSetAttribute((const void*)g3b_fc2p, hipFuncAttributeMaxDynamicSharedMemorySize, 65536);

  // weight prep
  cast_k<<<2048, 256, 0, stream>>>(w_qkv, wqkv_bf, (6144 * 2048) / 4);
  colnorm_k<<<32, 256, 0, stream>>>(apv, apg, s_attn, 2048, 2048);
  scale_cast_k<<<2048, 256, 0, stream>>>(apv, s_attn, wproj_bf, 2048, (2048 * 2048) / 4);
  colnorm_k<<<128, 256, 0, stream>>>(mpv, mpg, s_mlp, 2048, 8192);

  // LN1 -> xln (bf16)
  ln_k<<<4096, 256, 0, stream>>>(hidden, ln1_g, ln1_b, xln);

  // GEMM1 (128^2 2-phase, 1536 blocks): qkv -> q/k/v
  GemmP p1 = {xln, wqkv_bf, b_qkv, nullptr, nullptr, nullptr,
              qbuf, kbuf, vbuf, 4096, 6144, 2048};
  g1_qkv128<<<1536, 256, 0, stream>>>(p1);

  // V -> V^T
  vtrans_k<<<1024, 256, 0, stream>>>(vbuf, vtbuf);

  // attention -> attn_out (xln slot)
  attn_k<<<1024, 256, 0, stream>>>(qbuf, kbuf, vtbuf, xln);

  // weight casts for MLP
  cast_k<<<2048, 256, 0, stream>>>(w_fc, wfc_bf, (8192 * 2048) / 4);
  scale_cast_k<<<4096, 256, 0, stream>>>(mpv, s_mlp, w2_bf, 8192, (2048 * 8192) / 4);

  // GEMM2 (128^2): hidden2 = attn_out @ w_proj^T + b + hidden
  GemmP p2 = {xln, wproj_bf, apb, hidden, hidden2, nullptr,
              nullptr, nullptr, nullptr, 4096, 2048, 2048};
  g2_proj128<<<512, 256, 0, stream>>>(p2);

  // LN2 -> xln2
  ln_k<<<4096, 256, 0, stream>>>(hidden2, ln2_g, ln2_b, xln2);

  // GEMM3 A/B experiment: rows 0-2047 8-phase, rows 2048-4095 2-phase
  GemmP p3 = {xln2, wfc_bf, b_fc, nullptr, nullptr, hbuf,
              nullptr, nullptr, nullptr, 4096, 8192, 2048};
  g3a_fc8p<<<256, 512, 131072, stream>>>(p3);
  g3b_fc2p<<<256, 512, 65536, stream>>>(p3);

  // GEMM4 split-K x2 (1024 blocks) -> partials, then fused reduce
  GemmP p4 = {hbuf, w2_bf, mpb, nullptr, part0, nullptr,
              nullptr, nullptr, nullptr, 4096, 2048, 8192};
  g4_splitk<<<1024, 256, 0, stream>>>(p4);
  g4red_k<<<2048, 256, 0, stream>>>(part0, part1, mpb, hidden2, (float*)d_out,
                                    (4096 * 2048) / 4);
}

// Round 6
// 887.735 us; speedup vs baseline: 1.4420x; 1.4166x over previous
//
#include <hip/hip_runtime.h>
#include <hip/hip_bf16.h>

#define DEVI __device__ __forceinline__

typedef __attribute__((ext_vector_type(8))) __bf16 bf16x8;
typedef __attribute__((ext_vector_type(4))) float f32x4;
typedef __attribute__((ext_vector_type(4))) unsigned short u16x4;
typedef __attribute__((ext_vector_type(8))) unsigned short u16x8;

DEVI unsigned short f2bf(float f) {
  unsigned int u = __float_as_uint(f);
  u += 0x7FFFu + ((u >> 16) & 1u);   // RNE
  return (unsigned short)(u >> 16);
}

#define GLD16(g, l) __builtin_amdgcn_global_load_lds(                      \
    (const __attribute__((address_space(1))) void*)(g),                    \
    (__attribute__((address_space(3))) void*)(l), 16, 0, 0)

// ---------------------------------------------------------------- helpers

__global__ __launch_bounds__(256) void cast_k(const float* __restrict__ in,
                                              unsigned short* __restrict__ out,
                                              int n4) {
  for (int i = blockIdx.x * 256 + threadIdx.x; i < n4; i += gridDim.x * 256) {
    f32x4 v = ((const f32x4*)in)[i];
    u16x4 o;
    o.x = f2bf(v.x); o.y = f2bf(v.y); o.z = f2bf(v.z); o.w = f2bf(v.w);
    ((u16x4*)out)[i] = o;
  }
}

// colnorm phase 1: partial column sumsq over a 64-row x 512-col tile.
// grid = (cols/512, rows/64); fully coalesced f32x4 loads (1 KiB/wave/iter).
__global__ __launch_bounds__(256) void colnorm1_k(const float* __restrict__ v,
                                                  float* __restrict__ part,
                                                  int cols) {
  const int tid = threadIdx.x;
  const int g = tid & 127;          // f32x4 group within the 512-col span
  const int s = tid >> 7;           // row stripe 0/1 (32 rows each)
  const int c0 = blockIdx.x * 512;
  const int r0 = blockIdx.y * 64 + s * 32;
  const float* base = v + (size_t)r0 * cols + c0 + g * 4;
  f32x4 acc = {};
#pragma unroll 4
  for (int i = 0; i < 32; ++i) {
    f32x4 x = *(const f32x4*)(base + (size_t)i * cols);
    acc.x += x.x * x.x; acc.y += x.y * x.y;
    acc.z += x.z * x.z; acc.w += x.w * x.w;
  }
  __shared__ f32x4 red[256];
  red[tid] = acc;
  __syncthreads();
  if (s == 0) {
    f32x4 a = red[tid], b = red[tid + 128];
    f32x4 o;
    o.x = a.x + b.x; o.y = a.y + b.y; o.z = a.z + b.z; o.w = a.w + b.w;
    *(f32x4*)(part + (size_t)blockIdx.y * cols + c0 + g * 4) = o;
  }
}

// colnorm phase 2: s[c] = g[c] * rsqrt(sum_rc part[rc][c])
__global__ __launch_bounds__(256) void colnorm2_k(const float* __restrict__ part,
                                                  const float* __restrict__ g,
                                                  float* __restrict__ s,
                                                  int cols, int nrc) {
  const int c = blockIdx.x * 256 + threadIdx.x;
  float acc = 0.f;
  for (int i = 0; i < nrc; ++i) acc += part[(size_t)i * cols + c];
  s[c] = g[c] * rsqrtf(acc);
}

__global__ __launch_bounds__(256) void scale_cast_k(const float* __restrict__ in,
                                                    const float* __restrict__ s,
                                                    unsigned short* __restrict__ out,
                                                    int cols, int n4) {
  const int cmask4 = (cols >> 2) - 1;
  for (int i = blockIdx.x * 256 + threadIdx.x; i < n4; i += gridDim.x * 256) {
    f32x4 v = ((const f32x4*)in)[i];
    f32x4 sv = ((const f32x4*)s)[i & cmask4];
    u16x4 o;
    o.x = f2bf(v.x * sv.x); o.y = f2bf(v.y * sv.y);
    o.z = f2bf(v.z * sv.z); o.w = f2bf(v.w * sv.w);
    ((u16x4*)out)[i] = o;
  }
}

// LayerNorm: one block per row of 2048 fp32, out bf16
__global__ __launch_bounds__(256) void ln_k(const float* __restrict__ x,
                                            const float* __restrict__ g,
                                            const float* __restrict__ b,
                                            unsigned short* __restrict__ out) {
  const int tid = threadIdx.x, lane = tid & 63, wid = tid >> 6;
  const int row = blockIdx.x;
  const float* xr = x + (size_t)row * 2048;
  f32x4 a0 = ((const f32x4*)xr)[tid];
  f32x4 a1 = ((const f32x4*)xr)[tid + 256];
  float s = a0.x + a0.y + a0.z + a0.w + a1.x + a1.y + a1.z + a1.w;
  float ss = a0.x * a0.x + a0.y * a0.y + a0.z * a0.z + a0.w * a0.w +
             a1.x * a1.x + a1.y * a1.y + a1.z * a1.z + a1.w * a1.w;
#pragma unroll
  for (int m = 1; m < 64; m <<= 1) {
    s += __shfl_xor(s, m);
    ss += __shfl_xor(ss, m);
  }
  __shared__ float red[8];
  if (lane == 0) { red[wid] = s; red[4 + wid] = ss; }
  __syncthreads();
  s = red[0] + red[1] + red[2] + red[3];
  ss = red[4] + red[5] + red[6] + red[7];
  const float mu = s * (1.f / 2048.f);
  const float var = ss * (1.f / 2048.f) - mu * mu;
  const float rs = rsqrtf(var + 1e-5f);
  f32x4 g0 = ((const f32x4*)g)[tid], g1 = ((const f32x4*)g)[tid + 256];
  f32x4 b0 = ((const f32x4*)b)[tid], b1 = ((const f32x4*)b)[tid + 256];
  u16x4 o0, o1;
  o0.x = f2bf((a0.x - mu) * rs * g0.x + b0.x);
  o0.y = f2bf((a0.y - mu) * rs * g0.y + b0.y);
  o0.z = f2bf((a0.z - mu) * rs * g0.z + b0.z);
  o0.w = f2bf((a0.w - mu) * rs * g0.w + b0.w);
  o1.x = f2bf((a1.x - mu) * rs * g1.x + b1.x);
  o1.y = f2bf((a1.y - mu) * rs * g1.y + b1.y);
  o1.z = f2bf((a1.z - mu) * rs * g1.z + b1.z);
  o1.w = f2bf((a1.w - mu) * rs * g1.w + b1.w);
  unsigned short* orow = out + (size_t)row * 2048;
  *(u16x4*)(orow + 4 * tid) = o0;
  *(u16x4*)(orow + 1024 + 4 * tid) = o1;
}

// V transpose: v [32][2048][128] -> vt [32][128][2048]
__global__ __launch_bounds__(256) void vtrans_k(const unsigned short* __restrict__ v,
                                                unsigned short* __restrict__ vt) {
  __shared__ unsigned short t[64][134];
  const int tid = threadIdx.x;
  const int bh = blockIdx.x >> 5, st = blockIdx.x & 31;
  const unsigned short* vb = v + ((size_t)bh << 18) + ((size_t)(st << 6) << 7);
#pragma unroll
  for (int i = 0; i < 4; ++i) {
    int f = tid + (i << 8);
    int row = f >> 4, c8 = f & 15;
    u16x8 x = *(const u16x8*)(vb + row * 128 + c8 * 8);
#pragma unroll
    for (int j = 0; j < 4; ++j) {
      unsigned int pk = ((unsigned int)x[2 * j + 1] << 16) | x[2 * j];
      *(unsigned int*)&t[row][c8 * 8 + 2 * j] = pk;
    }
  }
  __syncthreads();
  const int lane = tid & 63, wid = tid >> 6;
  unsigned short* ob = vt + ((size_t)bh << 18) + (st << 6);
#pragma unroll
  for (int j = 0; j < 32; ++j) {
    int d = (wid << 5) + j;
    ob[((size_t)d << 11) + lane] = t[lane][d];
  }
}

// split-K reduce: out = part0 + part1 + bias + res  (all fp32, N=2048 rows)
__global__ __launch_bounds__(256) void g4red_k(const float* __restrict__ p0,
                                               const float* __restrict__ p1,
                                               const float* __restrict__ bias,
                                               const float* __restrict__ res,
                                               float* __restrict__ out, int n4) {
  for (int i = blockIdx.x * 256 + threadIdx.x; i < n4; i += gridDim.x * 256) {
    f32x4 a = ((const f32x4*)p0)[i];
    f32x4 b = ((const f32x4*)p1)[i];
    f32x4 r = ((const f32x4*)res)[i];
    f32x4 bb = ((const f32x4*)bias)[i & 511];   // 2048/4 - 1
    f32x4 o;
    o.x = a.x + b.x + r.x + bb.x;
    o.y = a.y + b.y + r.y + bb.y;
    o.z = a.z + b.z + r.z + bb.z;
    o.w = a.w + b.w + r.w + bb.w;
    ((f32x4*)out)[i] = o;
  }
}

// ---------------------------------------------------------------- GEMM params
struct GemmP {
  const unsigned short* A;
  const unsigned short* B;
  const float* bias;
  const float* res;
  float* outF;
  unsigned short* outH;
  unsigned short* q;
  unsigned short* k;
  unsigned short* vt;   // EPI0: v (row-major [B,H,S,D])
  int M, N, K;
};

// ---------------------------------------------------------------- 128^2 GEMM (2-phase)
// EPI: 0 = +bias scatter q/k/v  1 = +bias+res -> fp32  4 = raw partial -> fp32
template <int EPI>
DEVI void gemm128_body(const GemmP& p, int m0, int n0, int k0, int nk) {
  const int tid = threadIdx.x, lane = tid & 63, wid = tid >> 6;
  const int K = p.K;
  const int wr = wid >> 1, wc = wid & 1;

  __shared__ __align__(16) unsigned short sA[2][4096];
  __shared__ __align__(16) unsigned short sB[2][4096];

  const int c0 = tid, c1 = tid + 256;
  const unsigned short* gA0 = p.A + (size_t)(m0 + (c0 >> 2)) * K + k0 + ((c0 & 3) << 3);
  const unsigned short* gA1 = p.A + (size_t)(m0 + (c1 >> 2)) * K + k0 + ((c1 & 3) << 3);
  const unsigned short* gB0 = p.B + (size_t)(n0 + (c0 >> 2)) * K + k0 + ((c0 & 3) << 3);
  const unsigned short* gB1 = p.B + (size_t)(n0 + (c1 >> 2)) * K + k0 + ((c1 & 3) << 3);
  const int l0 = wid << 9, l1 = (wid << 9) + 2048;

  f32x4 acc[4][4] = {};
  const int arow = (wr << 6) + (lane & 15);
  const int brow = (wc << 6) + (lane & 15);
  const int koff = (lane >> 4) << 3;

#define STAGE128(bufi, t) do { int ko = (t) << 5;       \
    GLD16(gA0 + ko, &sA[bufi][l0]);                     \
    GLD16(gA1 + ko, &sA[bufi][l1]);                     \
    GLD16(gB0 + ko, &sB[bufi][l0]);                     \
    GLD16(gB1 + ko, &sB[bufi][l1]); } while (0)

  STAGE128(0, 0);
  __syncthreads();
  int cur = 0;
  for (int t = 0; t < nk; ++t) {
    if (t + 1 < nk) STAGE128(cur ^ 1, t + 1);
    bf16x8 af[4], bfr[4];
#pragma unroll
    for (int i = 0; i < 4; ++i)
      af[i] = *(const bf16x8*)&sA[cur][(arow + (i << 4)) * 32 + koff];
#pragma unroll
    for (int i = 0; i < 4; ++i)
      bfr[i] = *(const bf16x8*)&sB[cur][(brow + (i << 4)) * 32 + koff];
#pragma unroll
    for (int i = 0; i < 4; ++i)
#pragma unroll
      for (int j = 0; j < 4; ++j)
        acc[i][j] = __builtin_amdgcn_mfma_f32_16x16x32_bf16(af[i], bfr[j], acc[i][j], 0, 0, 0);
    __syncthreads();
    cur ^= 1;
  }
#undef STAGE128

  const int rbase = m0 + (wr << 6) + ((lane >> 4) << 2);
  const int cbase = n0 + (wc << 6) + (lane & 15);
#pragma unroll
  for (int mi = 0; mi < 4; ++mi) {
#pragma unroll
    for (int ni = 0; ni < 4; ++ni) {
      const int col = cbase + (ni << 4);
#pragma unroll
      for (int r = 0; r < 4; ++r) {
        const int row = rbase + (mi << 4) + r;
        if constexpr (EPI == 0) {
          float v = acc[mi][ni][r] + p.bias[col];
          const int gsel = col >> 11, e = col & 2047;
          const int h = e >> 7, d = e & 127;
          const int b2 = row >> 11, sidx = row & 2047;
          const size_t off = ((size_t)(b2 * 16 + h) << 18) + ((size_t)sidx << 7) + d;
          unsigned short hv = f2bf(v);
          if (gsel == 0)      p.q[off] = hv;
          else if (gsel == 1) p.k[off] = hv;
          else                p.vt[off] = hv;   // v row-major; transposed later
        } else if constexpr (EPI == 1) {
          const size_t o = (size_t)row * p.N + col;
          p.outF[o] = acc[mi][ni][r] + p.bias[col] + p.res[o];
        } else {
          p.outF[(size_t)row * p.N + col] = acc[mi][ni][r];   // raw partial
        }
      }
    }
  }
}

// G1: M=4096,N=6144 -> nbm=32,nbn=48. Region/XCD = 32 rows x 6 cols, bm-fastest.
__global__ __launch_bounds__(256) void g1_qkv128(GemmP p) {
  const int x = blockIdx.x & 7, i = blockIdx.x >> 3;  // i in [0,192)
  const int bm = i & 31;
  const int bn = x * 6 + (i >> 5);
  gemm128_body<0>(p, bm << 7, bn << 7, 0, p.K >> 5);
}
// G2: M=4096,N=2048 -> nbm=32,nbn=16. Region/XCD = 8x8.
__global__ __launch_bounds__(256) void g2_proj128(GemmP p) {
  const int x = blockIdx.x & 7, i = blockIdx.x >> 3;  // i in [0,64)
  const int bm = (x >> 1) * 8 + (i >> 3);
  const int bn = (x & 1) * 8 + (i & 7);
  gemm128_body<1>(p, bm << 7, bn << 7, 0, p.K >> 5);
}
// G4 split-K: 1024 blocks; tile (bm,bn) x K-half ks; partial -> p.outF (+ks offset)
__global__ __launch_bounds__(256) void g4_splitk(GemmP p) {
  const int x = blockIdx.x & 7, i = blockIdx.x >> 3;  // i in [0,128)
  const int ks = i & 1, j = i >> 1;                   // j in [0,64)
  const int bm = (x >> 1) * 8 + (j >> 3);
  const int bn = (x & 1) * 8 + (j & 7);
  GemmP q = p;
  q.outF = p.outF + (size_t)ks * 4096 * 2048;
  gemm128_body<4>(q, bm << 7, bn << 7, ks << 12, 128);   // K-half = 4096 = 128 steps
}

// ---------------------------------------------------------------- 256^2 tile common
DEVI void setup256(const GemmP& p, int m0, int n0,
                   const unsigned short*& gsA0, const unsigned short*& gsA1,
                   const unsigned short*& gsB0, const unsigned short*& gsB1) {
  const int tid = threadIdx.x;
  int r_[2], c_[2];
#pragma unroll
  for (int j = 0; j < 2; ++j) {
    int d = tid * 16 + j * 8192;
    int w = (d & 1023) ^ (((d >> 9) & 1) << 5);   // st_16x32 involution
    r_[j] = ((d >> 10) << 4) + (w >> 6);
    c_[j] = (w & 63) >> 1;
  }
  gsA0 = p.A + (size_t)(m0 + r_[0]) * p.K + c_[0];
  gsA1 = p.A + (size_t)(m0 + r_[1]) * p.K + c_[1];
  gsB0 = p.B + (size_t)(n0 + r_[0]) * p.K + c_[0];
  gsB1 = p.B + (size_t)(n0 + r_[1]) * p.K + c_[1];
}

// epilogue: +bias, fast-GELU -> bf16
DEVI void epi256g(const GemmP& p, f32x4 (&acc)[8][4], int m0, int n0) {
  const int lane = threadIdx.x & 63, wid = threadIdx.x >> 6;
  const int wr = wid >> 2, wc = wid & 3;
  const int lr = lane & 15, lk = lane >> 4;
  const int rbase = m0 + wr * 128 + (lk << 2);
  const int cbase = n0 + wc * 64 + lr;
#pragma unroll
  for (int m = 0; m < 8; ++m) {
#pragma unroll
    for (int n = 0; n < 4; ++n) {
      const int col = cbase + (n << 4);
      const float bb = p.bias[col];
#pragma unroll
      for (int r = 0; r < 4; ++r) {
        const int row = rbase + (m << 4) + r;
        float v = acc[m][n][r] + bb;
        float y = 0.7978845608028654f * (v + 0.044715f * v * v * v);
        float u = __expf(2.f * y);
        float gl = (y > 40.f) ? v : v * (u / (u + 1.f));
        p.outH[(size_t)row * p.N + col] = f2bf(gl);
      }
    }
  }
}

// ---------------------------------------------------------------- 256^2 8-phase (A arm)
DEVI void gemm8p_body(const GemmP& p, unsigned short* lds_raw, int m0, int n0) {
  const int tid = threadIdx.x, lane = tid & 63, wid = tid >> 6;
  const int wr = wid >> 2, wc = wid & 3;
  const int lr = lane & 15, lk = lane >> 4;
  const int fb = (lr * 64 + lk * 16) ^ ((lr & 8) << 2);

  const unsigned short *gsA0, *gsA1, *gsB0, *gsB1;
  setup256(p, m0, n0, gsA0, gsA1, gsB0, gsB1);

#define STAGE_A8(b, kt) do { unsigned short* _d = lds_raw + ((b) << 14);       \
    GLD16(gsA0 + ((size_t)(kt) << 5), _d + (tid << 3));                        \
    GLD16(gsA1 + ((size_t)(kt) << 5), _d + 4096 + (tid << 3)); } while (0)
#define STAGE_B8(b, kt) do { unsigned short* _d = lds_raw + ((b) << 14) + 8192;\
    GLD16(gsB0 + ((size_t)(kt) << 5), _d + (tid << 3));                        \
    GLD16(gsB1 + ((size_t)(kt) << 5), _d + 4096 + (tid << 3)); } while (0)

  f32x4 acc[8][4] = {};
  const int NK = p.K >> 5;

  STAGE_A8(0, 0); STAGE_B8(0, 0);
  STAGE_A8(1, 1); STAGE_B8(1, 1);
  STAGE_A8(2, 2); STAGE_B8(2, 2);
  asm volatile("s_waitcnt vmcnt(8)" ::: "memory");
  __builtin_amdgcn_s_barrier();

  for (int t = 0; t < NK; ++t) {
    const int bi = t & 3;
    const char* tA = (const char*)(lds_raw + (bi << 14));
    const char* tB = (const char*)(lds_raw + (bi << 14) + 8192);
    bf16x8 a_[4], b_[4];
#pragma unroll
    for (int n = 0; n < 4; ++n)
      b_[n] = *(const bf16x8*)(tB + (((wc << 2) + n) << 10) + fb);
#pragma unroll
    for (int m = 0; m < 4; ++m)
      a_[m] = *(const bf16x8*)(tA + (((wr << 3) + m) << 10) + fb);
    if (t + 3 < NK) STAGE_A8((t + 3) & 3, t + 3);
    __builtin_amdgcn_s_barrier();
    asm volatile("s_waitcnt lgkmcnt(0)" ::: "memory");
    __builtin_amdgcn_sched_barrier(0);
    __builtin_amdgcn_s_setprio(1);
#pragma unroll
    for (int m = 0; m < 4; ++m)
#pragma unroll
      for (int n = 0; n < 4; ++n)
        acc[m][n] = __builtin_amdgcn_mfma_f32_16x16x32_bf16(a_[m], b_[n], acc[m][n], 0, 0, 0);
    __builtin_amdgcn_s_setprio(0);
    __builtin_amdgcn_s_barrier();
#pragma unroll
    for (int m = 0; m < 4; ++m)
      a_[m] = *(const bf16x8*)(tA + (((wr << 3) + 4 + m) << 10) + fb);
    if (t + 3 < NK) STAGE_B8((t + 3) & 3, t + 3);
    if (t + 3 < NK)      asm volatile("s_waitcnt vmcnt(8)" ::: "memory");
    else if (t + 2 < NK) asm volatile("s_waitcnt vmcnt(4)" ::: "memory");
    else if (t + 1 < NK) asm volatile("s_waitcnt vmcnt(0)" ::: "memory");
    __builtin_amdgcn_s_barrier();
    asm volatile("s_waitcnt lgkmcnt(0)" ::: "memory");
    __builtin_amdgcn_sched_barrier(0);
    __builtin_amdgcn_s_setprio(1);
#pragma unroll
    for (int m = 0; m < 4; ++m)
#pragma unroll
      for (int n = 0; n < 4; ++n)
        acc[4 + m][n] = __builtin_amdgcn_mfma_f32_16x16x32_bf16(a_[m], b_[n], acc[4 + m][n], 0, 0, 0);
    __builtin_amdgcn_s_setprio(0);
    __builtin_amdgcn_s_barrier();
  }
#undef STAGE_A8
#undef STAGE_B8
  epi256g(p, acc, m0, n0);
}

// ---------------------------------------------------------------- 256^2 2-phase (B arm)
DEVI void gemm2p_body(const GemmP& p, unsigned short* lds_raw, int m0, int n0) {
  const int tid = threadIdx.x, lane = tid & 63, wid = tid >> 6;
  const int wr = wid >> 2, wc = wid & 3;
  const int lr = lane & 15, lk = lane >> 4;
  const int fb = (lr * 64 + lk * 16) ^ ((lr & 8) << 2);

  const unsigned short *gsA0, *gsA1, *gsB0, *gsB1;
  setup256(p, m0, n0, gsA0, gsA1, gsB0, gsB1);

#define STG2(b, kt) do { unsigned short* _d = lds_raw + ((b) << 14);     \
    GLD16(gsA0 + ((size_t)(kt) << 5), _d + (tid << 3));                  \
    GLD16(gsA1 + ((size_t)(kt) << 5), _d + 4096 + (tid << 3));           \
    GLD16(gsB0 + ((size_t)(kt) << 5), _d + 8192 + (tid << 3));           \
    GLD16(gsB1 + ((size_t)(kt) << 5), _d + 12288 + (tid << 3)); } while (0)

  f32x4 acc[8][4] = {};
  const int NK = p.K >> 5;
  STG2(0, 0);
  __syncthreads();
  int cur = 0;
  for (int t = 0; t < NK; ++t) {
    if (t + 1 < NK) STG2(cur ^ 1, t + 1);
    const char* tA = (const char*)(lds_raw + (cur << 14));
    const char* tB = tA + 16384;
    bf16x8 a_[8], b_[4];
#pragma unroll
    for (int n = 0; n < 4; ++n)
      b_[n] = *(const bf16x8*)(tB + (((wc << 2) + n) << 10) + fb);
#pragma unroll
    for (int m = 0; m < 8; ++m)
      a_[m] = *(const bf16x8*)(tA + (((wr << 3) + m) << 10) + fb);
#pragma unroll
    for (int m = 0; m < 8; ++m)
#pragma unroll
      for (int n = 0; n < 4; ++n)
        acc[m][n] = __builtin_amdgcn_mfma_f32_16x16x32_bf16(a_[m], b_[n], acc[m][n], 0, 0, 0);
    __syncthreads();
    cur ^= 1;
  }
#undef STG2
  epi256g(p, acc, m0, n0);
}

// G3a: rows [0,2048), 8-phase. nbm=8,nbn=32; region 4x8 per XCD
__global__ __launch_bounds__(512, 2) void g3a_fc8p(GemmP p) {
  extern __shared__ unsigned short lds_raw[];
  const int x = blockIdx.x & 7, i = blockIdx.x >> 3;
  const int bm = (x >> 2) * 4 + (i >> 3);
  const int bn = (x & 3) * 8 + (i & 7);
  gemm8p_body(p, lds_raw, bm << 8, bn << 8);
}
// G3b: rows [2048,4096), 2-phase (A/B control)
__global__ __launch_bounds__(512, 2) void g3b_fc2p(GemmP p) {
  extern __shared__ unsigned short lds_raw[];
  const int x = blockIdx.x & 7, i = blockIdx.x >> 3;
  const int bm = (x >> 2) * 4 + (i >> 3);
  const int bn = (x & 3) * 8 + (i & 7);
  gemm2p_body(p, lds_raw, 2048 + (bm << 8), bn << 8);
}

// ---------------------------------------------------------------- attention
// Q,K in [B,H,S,D]; V^T in [B,H,D,S]; O bf16 [4096,2048].
// Reg-staged K/V prefetch (T14) + defer-max (T13) + setprio on MFMA (T5).
__global__ __launch_bounds__(256) void attn_k(const unsigned short* __restrict__ Q,
                                              const unsigned short* __restrict__ Kg,
                                              const unsigned short* __restrict__ Vt,
                                              unsigned short* __restrict__ O) {
  const int tid = threadIdx.x, lane = tid & 63, wid = tid >> 6;
  const int bid = blockIdx.x;
  const int pos = bid >> 3;
  const int bh = (bid & 7) * 4 + (pos >> 5);
  const int qt = pos & 31;
  const int q0 = qt * 64 + wid * 16;
  const int b = bh >> 4, h = bh & 15;

  __shared__ __align__(16) unsigned short sK[64 * 128];
  __shared__ __align__(16) unsigned short sV[128 * 64];
  __shared__ __align__(16) unsigned short sP[4][16 * 72];

  const unsigned short* Qb = Q + ((size_t)bh << 18);
  const unsigned short* Kb = Kg + ((size_t)bh << 18);
  const unsigned short* Vb = Vt + ((size_t)bh << 18);

  bf16x8 qf[4];
  {
    const unsigned short* qp = Qb + (size_t)(q0 + (lane & 15)) * 128 + ((lane >> 4) << 3);
#pragma unroll
    for (int kk = 0; kk < 4; ++kk) qf[kk] = *(const bf16x8*)(qp + kk * 32);
  }

  int koffs[4], voffs[4];
#pragma unroll
  for (int i = 0; i < 4; ++i) {
    const int c = tid + (i << 8);
    const int kv = c >> 4, jj = c & 15;
    const int js = (jj & 8) | ((jj ^ kv) & 7);
    koffs[i] = kv * 128 + (js << 3);
    const int d = c >> 3, j2 = c & 7;
    const int js2 = j2 ^ (d & 7);
    voffs[i] = d * 2048 + (js2 << 3);
  }
  u16x8 kreg[4], vreg[4];
  auto PREF = [&](int kt) {
    const int kv0 = kt << 6;
#pragma unroll
    for (int i = 0; i < 4; ++i) {
      kreg[i] = *(const u16x8*)(Kb + kv0 * 128 + koffs[i]);
      vreg[i] = *(const u16x8*)(Vb + kv0 + voffs[i]);
    }
  };

  f32x4 oacc[8] = {};
  float mrun = -3e38f, lrun = 0.f;
  PREF(0);

  for (int kt = 0; kt < 32; ++kt) {
#pragma unroll
    for (int i = 0; i < 4; ++i) {
      const int c8 = (tid + (i << 8)) << 3;
      *(u16x8*)&sK[c8] = kreg[i];
      *(u16x8*)&sV[c8] = vreg[i];
    }
    __syncthreads();
    if (kt + 1 < 32) PREF(kt + 1);

    f32x4 sc[4] = {};
    __builtin_amdgcn_s_setprio(1);
#pragma unroll
    for (int ti = 0; ti < 4; ++ti) {
#pragma unroll
      for (int kk = 0; kk < 4; ++kk) {
        const int row = (ti << 4) + (lane & 15);
        int bo = (row << 8) + (kk << 6) + ((lane >> 4) << 4);
        bo ^= (row & 7) << 4;
        bf16x8 kf = *(const bf16x8*)((const char*)sK + bo);
        sc[ti] = __builtin_amdgcn_mfma_f32_16x16x32_bf16(kf, qf[kk], sc[ti], 0, 0, 0);
      }
    }
    __builtin_amdgcn_s_setprio(0);

    float pv[16];
    float mx = -3e38f;
#pragma unroll
    for (int ti = 0; ti < 4; ++ti)
#pragma unroll
      for (int r = 0; r < 4; ++r) {
        float x = sc[ti][r] * 0.08838834764831845f;
        pv[(ti << 2) + r] = x;
        mx = fmaxf(mx, x);
      }
    mx = fmaxf(mx, __shfl_xor(mx, 16));
    mx = fmaxf(mx, __shfl_xor(mx, 32));

    float corr = 1.f;
    if (!__all(mx - mrun <= 8.f)) {
      const float mnew = fmaxf(mrun, mx);
      corr = __expf(mrun - mnew);
      mrun = mnew;
      float fr[4];
#pragma unroll
      for (int r = 0; r < 4; ++r) fr[r] = __shfl(corr, ((lane >> 4) << 2) + r);
#pragma unroll
      for (int di = 0; di < 8; ++di)
#pragma unroll
        for (int r = 0; r < 4; ++r) oacc[di][r] *= fr[r];
    }
    float psum = 0.f;
#pragma unroll
    for (int i2 = 0; i2 < 16; ++i2) {
      float e = __expf(pv[i2] - mrun);
      pv[i2] = e;
      psum += e;
    }
    psum += __shfl_xor(psum, 16);
    psum += __shfl_xor(psum, 32);
    lrun = lrun * corr + psum;

    unsigned short* prow = &sP[wid][(lane & 15) * 72];
#pragma unroll
    for (int ti = 0; ti < 4; ++ti) {
      u16x4 w4;
      w4.x = f2bf(pv[(ti << 2) + 0]);
      w4.y = f2bf(pv[(ti << 2) + 1]);
      w4.z = f2bf(pv[(ti << 2) + 2]);
      w4.w = f2bf(pv[(ti << 2) + 3]);
      *(u16x4*)&prow[(ti << 4) + ((lane >> 4) << 2)] = w4;
    }

    __builtin_amdgcn_s_setprio(1);
#pragma unroll
    for (int di = 0; di < 8; ++di) {
#pragma unroll
      for (int ks = 0; ks < 2; ++ks) {
        bf16x8 pf = *(const bf16x8*)((const char*)&sP[wid][0] +
                                     (lane & 15) * 144 + (ks << 6) + ((lane >> 4) << 4));
        const int dr = (di << 4) + (lane & 15);
        int bo = (dr << 7) + (ks << 6) + ((lane >> 4) << 4);
        bo ^= (dr & 7) << 4;
        bf16x8 vf = *(const bf16x8*)((const char*)sV + bo);
        oacc[di] = __builtin_amdgcn_mfma_f32_16x16x32_bf16(pf, vf, oacc[di], 0, 0, 0);
      }
    }
    __builtin_amdgcn_s_setprio(0);
    __syncthreads();
  }

  float il[4];
#pragma unroll
  for (int r = 0; r < 4; ++r) il[r] = 1.f / __shfl(lrun, ((lane >> 4) << 2) + r);
  const size_t obase = ((size_t)(b * 2048 + q0)) * 2048 + h * 128;
#pragma unroll
  for (int di = 0; di < 8; ++di)
#pragma unroll
    for (int r = 0; r < 4; ++r) {
      const size_t o = obase + (size_t)(((lane >> 4) << 2) + r) * 2048 + (di << 4) + (lane & 15);
      O[o] = f2bf(oacc[di][r] * il[r]);
    }
}

// ---------------------------------------------------------------- launch

extern "C" void kernel_launch(void* const* d_in, const int* in_sizes, int n_in,
                              void* d_out, int out_size, void* d_ws, size_t ws_size,
                              hipStream_t stream) {
  (void)in_sizes; (void)n_in; (void)out_size; (void)ws_size;
  const float* hidden = (const float*)d_in[0];
  const float* ln1_g = (const float*)d_in[1];
  const float* ln1_b = (const float*)d_in[2];
  const float* w_qkv = (const float*)d_in[3];
  const float* b_qkv = (const float*)d_in[4];
  const float* apv = (const float*)d_in[5];
  const float* apg = (const float*)d_in[6];
  const float* apb = (const float*)d_in[7];
  // d_in[8] emotion_bias: softmax-invariant -> dropped (exact)
  const float* ln2_g = (const float*)d_in[9];
  const float* ln2_b = (const float*)d_in[10];
  const float* w_fc = (const float*)d_in[11];
  const float* b_fc = (const float*)d_in[12];
  const float* mpv = (const float*)d_in[13];
  const float* mpg = (const float*)d_in[14];
  const float* mpb = (const float*)d_in[15];

  char* w = (char*)d_ws;
  const size_t MBs = 1ull << 20;
  float* hidden2 = (float*)(w + 0);                           // 32 MiB (live G2..end)
  unsigned short* vbuf = (unsigned short*)(w + 32 * MBs);     // 16 MiB (G1..vtrans)
  unsigned short* vtbuf = (unsigned short*)(w + 48 * MBs);    // 16 MiB (vtrans..attn)
  unsigned short* hbuf = (unsigned short*)(w + 32 * MBs);     // 64 MiB (G3..G4, after attn)
  unsigned short* qbuf = (unsigned short*)(w + 96 * MBs);     // 16 MiB
  unsigned short* kbuf = (unsigned short*)(w + 112 * MBs);    // 16 MiB
  unsigned short* xln = (unsigned short*)(w + 128 * MBs);     // 16 MiB (xln -> attn_out)
  unsigned short* xln2 = (unsigned short*)(w + 144 * MBs);    // 16 MiB
  unsigned short* wqkv_bf = (unsigned short*)(w + 160 * MBs); // 24 MiB (dead after G1)
  unsigned short* w2_bf = (unsigned short*)(w + 160 * MBs);   // 32 MiB (after G1)
  unsigned short* wproj_bf = (unsigned short*)(w + 192 * MBs);// 8 MiB
  float* s_attn = (float*)(w + 200 * MBs);                    // 8 KiB
  float* s_mlp = (float*)(w + 200 * MBs + 32768);             // 32 KiB
  float* part_attn = (float*)(w + 201 * MBs);                 // 256 KiB (32x2048)
  float* part_mlp = (float*)(w + 202 * MBs);                  // 1 MiB (32x8192)
  unsigned short* wfc_bf = qbuf;        // 32 MiB over dead q+k (after attn)
  float* part0 = (float*)(w + 96 * MBs);   // 32 MiB over dead qbuf/kbuf (at G4)
  float* part1 = (float*)(w + 128 * MBs);  // 32 MiB over dead xln/xln2 (at G4)

  hipFuncSetAttribute((const void*)g3a_fc8p, hipFuncAttributeMaxDynamicSharedMemorySize, 131072);
  hipFuncSetAttribute((const void*)g3b_fc2p, hipFuncAttributeMaxDynamicSharedMemorySize, 65536);

  // weight prep (colnorm: two-phase coalesced; was 2x ~227 us latency-bound)
  cast_k<<<2048, 256, 0, stream>>>(w_qkv, wqkv_bf, (6144 * 2048) / 4);
  colnorm1_k<<<dim3(4, 32), 256, 0, stream>>>(apv, part_attn, 2048);
  colnorm2_k<<<8, 256, 0, stream>>>(part_attn, apg, s_attn, 2048, 32);
  scale_cast_k<<<2048, 256, 0, stream>>>(apv, s_attn, wproj_bf, 2048, (2048 * 2048) / 4);
  colnorm1_k<<<dim3(16, 32), 256, 0, stream>>>(mpv, part_mlp, 8192);
  colnorm2_k<<<32, 256, 0, stream>>>(part_mlp, mpg, s_mlp, 8192, 32);

  // LN1 -> xln (bf16)
  ln_k<<<4096, 256, 0, stream>>>(hidden, ln1_g, ln1_b, xln);

  // GEMM1 (128^2 2-phase, 1536 blocks): qkv -> q/k/v
  GemmP p1 = {xln, wqkv_bf, b_qkv, nullptr, nullptr, nullptr,
              qbuf, kbuf, vbuf, 4096, 6144, 2048};
  g1_qkv128<<<1536, 256, 0, stream>>>(p1);

  // V -> V^T
  vtrans_k<<<1024, 256, 0, stream>>>(vbuf, vtbuf);

  // attention -> attn_out (xln slot)
  attn_k<<<1024, 256, 0, stream>>>(qbuf, kbuf, vtbuf, xln);

  // weight casts for MLP
  cast_k<<<2048, 256, 0, stream>>>(w_fc, wfc_bf, (8192 * 2048) / 4);
  scale_cast_k<<<4096, 256, 0, stream>>>(mpv, s_mlp, w2_bf, 8192, (2048 * 8192) / 4);

  // GEMM2 (128^2): hidden2 = attn_out @ w_proj^T + b + hidden
  GemmP p2 = {xln, wproj_bf, apb, hidden, hidden2, nullptr,
              nullptr, nullptr, nullptr, 4096, 2048, 2048};
  g2_proj128<<<512, 256, 0, stream>>>(p2);

  // LN2 -> xln2
  ln_k<<<4096, 256, 0, stream>>>(hidden2, ln2_g, ln2_b, xln2);

  // GEMM3 A/B experiment: rows 0-2047 8-phase, rows 2048-4095 2-phase
  GemmP p3 = {xln2, wfc_bf, b_fc, nullptr, nullptr, hbuf,
              nullptr, nullptr, nullptr, 4096, 8192, 2048};
  g3a_fc8p<<<256, 512, 131072, stream>>>(p3);
  g3b_fc2p<<<256, 512, 65536, stream>>>(p3);

  // GEMM4 split-K x2 (1024 blocks) -> partials, then fused reduce
  GemmP p4 = {hbuf, w2_bf, mpb, nullptr, part0, nullptr,
              nullptr, nullptr, nullptr, 4096, 2048, 8192};
  g4_splitk<<<1024, 256, 0, stream>>>(p4);
  g4red_k<<<2048, 256, 0, stream>>>(part0, part1, mpb, hidden2, (float*)d_out,
                                    (4096 * 2048) / 4);
}